// Round 14
// baseline (229.457 us; speedup 1.0000x reference)
//
#include <hip/hip_runtime.h>
#include <math.h>

// Problem constants
#define BATCH 8
#define CH    256
#define HDIM  56
#define WDIM  56
#define HW    (HDIM*WDIM)          // 3136
#define MTOT  (BATCH*HW)           // 25088
#define GRP   8
#define GC    32
#define NP    9                    // K*K
#define NOFF  (GRP*NP*2)           // 144
#define NMSK  (GRP*NP)             // 72
#define NTOT  (NOFF+NMSK)          // 216
#define POSB  4                    // positions per sample block (fallback)
#define SPOS  8                    // positions per sample block (main path)
#define DWBLK (MTOT/POSB)          // 6272 (fallback dw / sample grid)
#define DW2BLK (MTOT/8)            // 3136 (main-path dw: 8 pos/block)
#define SBLK  (MTOT/SPOS)          // 3136 (main-path sample grid)
#define XTBLK (49*4*8)             // 1568 xt-split blocks
#define NBLKG ((MTOT/64)*2)        // 784: 392 m-tiles(64) x 2 n-tiles(128)

typedef float f32x4 __attribute__((ext_vector_type(4)));
typedef short s16x8 __attribute__((ext_vector_type(8)));

// split a,b into packed bf16 hi (truncation) and bf16 lo (exact remainder, truncated)
__device__ inline void split2(float a, float b, unsigned int& hp, unsigned int& lp)
{
    const unsigned int ua = __float_as_uint(a), ub = __float_as_uint(b);
    hp = (ub & 0xffff0000u) | (ua >> 16);
    const float ha = __uint_as_float(ua & 0xffff0000u);
    const float hb = __uint_as_float(ub & 0xffff0000u);
    const unsigned int la = __float_as_uint(a - ha), lb = __float_as_uint(b - hb);
    lp = (lb & 0xffff0000u) | (la >> 16);
}

// async global(16B/lane) -> LDS (wave-uniform base + lane*16)
__device__ __forceinline__ void gld_lds16(const unsigned short* g, unsigned short* l)
{
    __builtin_amdgcn_global_load_lds(
        (const __attribute__((address_space(1))) unsigned int*)g,
        (__attribute__((address_space(3))) unsigned int*)l, 16, 0, 0);
}

// ---------------------------------------------------------------------------
// 64m x 128n LDS-staged GEMM body (r10/r11-verified).
// ---------------------------------------------------------------------------
__device__ __forceinline__ void gemm64x128_body(
    const unsigned short* __restrict__ ahi,
    const unsigned short* __restrict__ alo,
    const unsigned short* __restrict__ whi,
    const unsigned short* __restrict__ wlo,
    unsigned short* sAh, unsigned short* sAl,
    unsigned short* sBh, unsigned short* sBl,
    int m0, int n0g, int t, f32x4 (&acc)[4][2])
{
    const int lane = t & 63, wv4 = t >> 6;
    const int wm = wv4 >> 1;
    const int wn = wv4 & 1;
    const int fm = lane & 15, q = lane >> 4;

    const int arow0 = t >> 2;
    const int asl0  = (t & 3) ^ ((arow0 >> 1) & 3);
    const int albase0 = wv4 * 512;             // shorts; wave-uniform
    int brow[2], bsl[2], blbase[2];
    #pragma unroll
    for (int i = 0; i < 2; ++i) {
        const int u = i * 256 + t;
        brow[i] = u >> 2;
        bsl[i] = (u & 3) ^ ((brow[i] >> 1) & 3);
        blbase[i] = i * 2048 + wv4 * 512;
    }

    for (int kk = 0; kk < 8; ++kk) {
        const int k0 = kk * 32;
        {
            const size_t ga = (size_t)(m0 + arow0) * CH + k0 + asl0 * 8;
            gld_lds16(ahi + ga, sAh + albase0);
            gld_lds16(alo + ga, sAl + albase0);
        }
        #pragma unroll
        for (int i = 0; i < 2; ++i) {
            const size_t gb = (size_t)(n0g + brow[i]) * CH + k0 + bsl[i] * 8;
            gld_lds16(whi + gb, sBh + blbase[i]);
            gld_lds16(wlo + gb, sBl + blbase[i]);
        }
        __syncthreads();

        s16x8 ah[2], al[2], wh[4], wl[4];
        #pragma unroll
        for (int i = 0; i < 2; ++i) {
            const int ar = wm * 32 + i * 16 + fm;
            const int as = (q ^ ((ar >> 1) & 3)) * 8;
            ah[i] = *(const s16x8*)&sAh[ar * 32 + as];
            al[i] = *(const s16x8*)&sAl[ar * 32 + as];
        }
        #pragma unroll
        for (int i = 0; i < 4; ++i) {
            const int br = wn * 64 + i * 16 + fm;
            const int bs = (q ^ ((br >> 1) & 3)) * 8;
            wh[i] = *(const s16x8*)&sBh[br * 32 + bs];
            wl[i] = *(const s16x8*)&sBl[br * 32 + bs];
        }
        #pragma unroll
        for (int nt = 0; nt < 4; ++nt)
            #pragma unroll
            for (int mt = 0; mt < 2; ++mt) {
                acc[nt][mt] = __builtin_amdgcn_mfma_f32_16x16x32_bf16(wh[nt], ah[mt], acc[nt][mt], 0, 0, 0);
                acc[nt][mt] = __builtin_amdgcn_mfma_f32_16x16x32_bf16(wh[nt], al[mt], acc[nt][mt], 0, 0, 0);
                acc[nt][mt] = __builtin_amdgcn_mfma_f32_16x16x32_bf16(wl[nt], ah[mt], acc[nt][mt], 0, 0, 0);
            }
        __syncthreads();
    }
}

// ---------------------------------------------------------------------------
// PREP: xt_split + wt_splits + wt2_split(+bcat), one dispatch. (r11-verified)
// ---------------------------------------------------------------------------
__global__ __launch_bounds__(256)
void prep_kernel(const float* __restrict__ x,
                 unsigned short* __restrict__ xt_hi,
                 unsigned short* __restrict__ xt_lo,
                 const float* __restrict__ w_out,
                 unsigned short* __restrict__ wt_hi,
                 unsigned short* __restrict__ wt_lo,
                 const float* __restrict__ w_in,
                 unsigned short* __restrict__ wt3_hi,
                 unsigned short* __restrict__ wt3_lo,
                 const float* __restrict__ w_off,
                 const float* __restrict__ w_mask,
                 const float* __restrict__ b_off,
                 const float* __restrict__ b_mask,
                 unsigned short* __restrict__ wt2_hi,
                 unsigned short* __restrict__ wt2_lo,
                 float* __restrict__ bcat)
{
    __shared__ float lds[64][68];
    const int bid = blockIdx.x;
    const int t = threadIdx.x;

    if (bid < XTBLK) {
        const int hw0 = (bid % 49) * 64;
        const int k0  = ((bid / 49) % 4) * 64;
        const int b   = bid / 196;
        #pragma unroll
        for (int p = 0; p < 4; ++p) {
            const int kr = (t >> 4) + p * 16;
            const int hc = (t & 15) * 4;
            *(float4*)&lds[kr][hc] =
                *(const float4*)(x + ((size_t)b * CH + k0 + kr) * HW + hw0 + hc);
        }
        __syncthreads();
        const int ml = t >> 2;
        const int kc = (t & 3) * 16;
        unsigned int hbuf[8], lbuf[8];
        #pragma unroll
        for (int j = 0; j < 16; j += 2)
            split2(lds[kc + j][ml], lds[kc + j + 1][ml], hbuf[j >> 1], lbuf[j >> 1]);
        const size_t row = (size_t)(b * HW + hw0 + ml) * CH + k0 + kc;
        *(uint4*)&xt_hi[row]     = *(uint4*)&hbuf[0];
        *(uint4*)&xt_hi[row + 8] = *(uint4*)&hbuf[4];
        *(uint4*)&xt_lo[row]     = *(uint4*)&lbuf[0];
        *(uint4*)&xt_lo[row + 8] = *(uint4*)&lbuf[4];
    } else if (bid < XTBLK + 32) {
        const int u = bid - XTBLK;
        const float* w = (u < 16) ? w_out : w_in;
        unsigned short* hi = (u < 16) ? wt_hi : wt3_hi;
        unsigned short* lo = (u < 16) ? wt_lo : wt3_lo;
        const int uu = u & 15;
        const int kt = (uu & 3) * 64, nt = (uu >> 2) * 64;
        #pragma unroll
        for (int p = 0; p < 4; ++p) {
            const int kr = (t >> 4) + p * 16, nc = (t & 15) * 4;
            *(float4*)&lds[kr][nc] = *(const float4*)(w + (size_t)(kt + kr) * CH + nt + nc);
        }
        __syncthreads();
        const int nl = t >> 2, kc = (t & 3) * 16;
        #pragma unroll
        for (int j = 0; j < 16; j += 2) {
            const float f0 = lds[kc + j][nl], f1 = lds[kc + j + 1][nl];
            unsigned int hp, lp;
            split2(f0, f1, hp, lp);
            *(unsigned int*)&hi[(size_t)(nt + nl) * CH + kt + kc + j] = hp;
            *(unsigned int*)&lo[(size_t)(nt + nl) * CH + kt + kc + j] = lp;
        }
    } else {
        const int u = bid - XTBLK - 32;    // 0..15
        const int n = t;
        if (u == 0) {
            bcat[n] = (n < NOFF) ? b_off[n] : ((n < NTOT) ? b_mask[n - NOFF] : 0.0f);
        }
        const int k0 = u * 16;
        #pragma unroll
        for (int j = 0; j < 16; j += 2) {
            const int k = k0 + j;
            float f0 = 0.0f, f1 = 0.0f;
            if (n < NOFF) {
                f0 = w_off[(size_t)k * NOFF + n];
                f1 = w_off[(size_t)(k + 1) * NOFF + n];
            } else if (n < NTOT) {
                f0 = w_mask[(size_t)k * NMSK + (n - NOFF)];
                f1 = w_mask[(size_t)(k + 1) * NMSK + (n - NOFF)];
            }
            unsigned int hp, lp;
            split2(f0, f1, hp, lp);
            *(unsigned int*)&wt2_hi[(size_t)n * CH + k] = hp;
            *(unsigned int*)&wt2_lo[(size_t)n * CH + k] = lp;
        }
    }
}

// ---------------------------------------------------------------------------
// dw, 2 positions per wave (r13-verified neutral-correct).
// ---------------------------------------------------------------------------
__global__ __launch_bounds__(256)
void dw2_ln_gelu_split(const unsigned short* __restrict__ xhi,
                       const unsigned short* __restrict__ xlo,
                       const float* __restrict__ dw_w,
                       const float* __restrict__ dw_b,
                       const float* __restrict__ ln_g,
                       const float* __restrict__ ln_b,
                       unsigned short* __restrict__ fh,
                       unsigned short* __restrict__ fl)
{
    __shared__ float wt[NP][CH];
    __shared__ float lbias[CH], lgam[CH], lbet[CH];
    const int t = threadIdx.x;
    {
        const float* wp = dw_w + t * NP;
        #pragma unroll
        for (int p = 0; p < NP; ++p) wt[p][t] = wp[p];
        lbias[t] = dw_b[t]; lgam[t] = ln_g[t]; lbet[t] = ln_b[t];
    }
    __syncthreads();

    const int per  = DW2BLK / 8;           // 392
    const int bid  = blockIdx.x;
    const int sw   = (bid & 7) * per + (bid >> 3);
    const int wv   = t >> 6, lane = t & 63;
    const int c4   = lane * 4;
    const float4 b4 = *(const float4*)&lbias[c4];
    const float4 g4 = *(const float4*)&lgam[c4];
    const float4 e4 = *(const float4*)&lbet[c4];

    #pragma unroll
    for (int i = 0; i < 2; ++i) {
        const int n  = sw * 8 + wv * 2 + i;
        const int b  = n / HW;
        const int hw = n % HW;
        const int h  = hw / WDIM, w = hw % WDIM;
        const size_t base = (size_t)b * HW * CH + c4;

        float ax = 0.0f, ay = 0.0f, az = 0.0f, aw = 0.0f;
        #pragma unroll
        for (int p = 0; p < NP; ++p) {
            const int hh = h + p / 3 - 1;
            const int ww = w + p % 3 - 1;
            if ((unsigned)hh >= (unsigned)HDIM || (unsigned)ww >= (unsigned)WDIM)
                continue;                   // wave-uniform branch (h,w per-wave)
            const size_t idx = base + (size_t)(hh * WDIM + ww) * CH;
            const ushort4 uh = *(const ushort4*)(xhi + idx);
            const ushort4 ul = *(const ushort4*)(xlo + idx);
            const float4 wv4 = *(const float4*)&wt[p][c4];
            ax = fmaf(__uint_as_float((unsigned)uh.x << 16), wv4.x,
                 fmaf(__uint_as_float((unsigned)ul.x << 16), wv4.x, ax));
            ay = fmaf(__uint_as_float((unsigned)uh.y << 16), wv4.y,
                 fmaf(__uint_as_float((unsigned)ul.y << 16), wv4.y, ay));
            az = fmaf(__uint_as_float((unsigned)uh.z << 16), wv4.z,
                 fmaf(__uint_as_float((unsigned)ul.z << 16), wv4.z, az));
            aw = fmaf(__uint_as_float((unsigned)uh.w << 16), wv4.w,
                 fmaf(__uint_as_float((unsigned)ul.w << 16), wv4.w, aw));
        }
        ax += b4.x; ay += b4.y; az += b4.z; aw += b4.w;

        float s1 = ax + ay + az + aw;
        float s2 = ax*ax + ay*ay + az*az + aw*aw;
        #pragma unroll
        for (int off = 32; off > 0; off >>= 1) {
            s1 += __shfl_xor(s1, off);
            s2 += __shfl_xor(s2, off);
        }
        const float mean = s1 * (1.0f / 256.0f);
        const float rstd = rsqrtf(s2 * (1.0f / 256.0f) - mean * mean + 1e-5f);

        const float x0 = (ax - mean) * rstd * g4.x + e4.x;
        const float x1 = (ay - mean) * rstd * g4.y + e4.y;
        const float x2 = (az - mean) * rstd * g4.z + e4.z;
        const float x3 = (aw - mean) * rstd * g4.w + e4.w;
        const float o0 = 0.5f * x0 * (1.0f + erff(x0 * 0.70710678118654752f));
        const float o1 = 0.5f * x1 * (1.0f + erff(x1 * 0.70710678118654752f));
        const float o2 = 0.5f * x2 * (1.0f + erff(x2 * 0.70710678118654752f));
        const float o3 = 0.5f * x3 * (1.0f + erff(x3 * 0.70710678118654752f));

        unsigned int hp0, lp0, hp1, lp1;
        split2(o0, o1, hp0, lp0);
        split2(o2, o3, hp1, lp1);
        *(uint2*)&fh[(size_t)n * CH + c4] = make_uint2(hp0, hp1);
        *(uint2*)&fl[(size_t)n * CH + c4] = make_uint2(lp0, lp1);
    }
}

// ---------------------------------------------------------------------------
// DUAL GEMM after dw (r12-verified).
// ---------------------------------------------------------------------------
__global__ __launch_bounds__(256)
void gemm_dual64(const unsigned short* __restrict__ ahi1,
                 const unsigned short* __restrict__ alo1,
                 const unsigned short* __restrict__ whi1,
                 const unsigned short* __restrict__ wlo1,
                 const float* __restrict__ bias1,
                 float* __restrict__ out1,
                 const unsigned short* __restrict__ ahi2,
                 const unsigned short* __restrict__ alo2,
                 const unsigned short* __restrict__ whi2,
                 const unsigned short* __restrict__ wlo2,
                 const float* __restrict__ bias2,
                 float* __restrict__ out2)
{
    __shared__ unsigned short sAh[64*32], sAl[64*32], sBh[128*32], sBl[128*32];

    const int half = blockIdx.x >= NBLKG;
    const int lbid = blockIdx.x - (half ? NBLKG : 0);
    const unsigned short* ahi = half ? ahi2 : ahi1;
    const unsigned short* alo = half ? alo2 : alo1;
    const unsigned short* whi = half ? whi2 : whi1;
    const unsigned short* wlo = half ? wlo2 : wlo1;
    const float* bias = half ? bias2 : bias1;
    float* out = half ? out2 : out1;

    const int sw = (lbid & 7) * (NBLKG / 8) + (lbid >> 3);   // bijective 784=8*98
    const int m0  = (sw >> 1) * 64;
    const int n0g = (sw & 1) * 128;
    const int t = threadIdx.x;
    const int lane = t & 63, wv4 = t >> 6;
    const int wm = wv4 >> 1, wn = wv4 & 1;
    const int fm = lane & 15, q = lane >> 4;

    f32x4 acc[4][2];
    const f32x4 zero = {0.0f, 0.0f, 0.0f, 0.0f};
    #pragma unroll
    for (int i = 0; i < 4; ++i)
        #pragma unroll
        for (int j = 0; j < 2; ++j) acc[i][j] = zero;

    gemm64x128_body(ahi, alo, whi, wlo, sAh, sAl, sBh, sBl, m0, n0g, t, acc);

    #pragma unroll
    for (int nt = 0; nt < 4; ++nt) {
        const int n = n0g + wn*64 + nt*16 + q*4;
        const float4 b4 = *(const float4*)&bias[n];
        #pragma unroll
        for (int mt = 0; mt < 2; ++mt) {
            const int mm = m0 + wm*32 + mt*16 + fm;
            f32x4 o = acc[nt][mt];
            o[0] += b4.x; o[1] += b4.y; o[2] += b4.z; o[3] += b4.w;
            *(f32x4*)&out[(size_t)mm * CH + n] = o;
        }
    }
}

// ---------------------------------------------------------------------------
// Output GEMM, 64m x 128n tiles (r10-verified): BN+SiLU NCHW epilogue.
// ---------------------------------------------------------------------------
__global__ __launch_bounds__(256)
void gemm_out_64x128(const unsigned short* __restrict__ ahi,
                     const unsigned short* __restrict__ alo,
                     const unsigned short* __restrict__ whi,
                     const unsigned short* __restrict__ wlo,
                     const float* __restrict__ bias,
                     const float* __restrict__ bn_g,
                     const float* __restrict__ bn_b,
                     const float* __restrict__ bn_mean,
                     const float* __restrict__ bn_var,
                     float* __restrict__ y)                  // [B,256,3136]
{
    __shared__ unsigned short sAh[64*32], sAl[64*32], sBh[128*32], sBl[128*32];

    const int sw = (blockIdx.x & 7) * (NBLKG / 8) + (blockIdx.x >> 3);
    const int m0  = (sw >> 1) * 64;
    const int n0g = (sw & 1) * 128;
    const int t = threadIdx.x;
    const int lane = t & 63, wv4 = t >> 6;
    const int wm = wv4 >> 1, wn = wv4 & 1;
    const int fm = lane & 15, q = lane >> 4;

    f32x4 acc[4][2];
    const f32x4 zero = {0.0f, 0.0f, 0.0f, 0.0f};
    #pragma unroll
    for (int i = 0; i < 4; ++i)
        #pragma unroll
        for (int j = 0; j < 2; ++j) acc[i][j] = zero;

    gemm64x128_body(ahi, alo, whi, wlo, sAh, sAl, sBh, sBl, m0, n0g, t, acc);

    #pragma unroll
    for (int nt = 0; nt < 4; ++nt) {
        #pragma unroll
        for (int r = 0; r < 4; ++r) {
            const int n = n0g + wn*64 + nt*16 + q*4 + r;
            const float sc = bn_g[n] * rsqrtf(bn_var[n] + 1e-5f);
            const float sb = bn_b[n] - bn_mean[n] * sc;
            const float bs = bias[n];
            #pragma unroll
            for (int mt = 0; mt < 2; ++mt) {
                const int mm = m0 + wm*32 + mt*16 + fm;
                const int bimg = mm / HW, hw = mm % HW;
                float val = (acc[nt][mt][r] + bs) * sc + sb;
                y[(size_t)bimg * CH * HW + (size_t)n * HW + hw] = val / (1.0f + expf(-val));
            }
        }
    }
}

// ---------------------------------------------------------------------------
// Sampling, 8 positions/block, 2 per wave in the gather (doubles MLP against
// L2 latency; halves per-position barrier/phase overhead; 64 softmax lanes
// active vs 32). Per-position math identical to r13 -> bit-identical output.
// Grid 3136 = 8 x 392 bijective XCD swizzle; 8 | 3136 so no batch straddle.
// ---------------------------------------------------------------------------
__global__ __launch_bounds__(256)
void sample8_omb_split(const float* __restrict__ v,
                       const float* __restrict__ omb,
                       unsigned short* __restrict__ sh,  // [MTOT][256]
                       unsigned short* __restrict__ sl)  // [MTOT][256]
{
    __shared__ alignas(16) float loff[SPOS][NOFF];
    __shared__ alignas(16) float lmsk[SPOS][NMSK];
    __shared__ alignas(16) float wtab[SPOS][GRP*NP][4];
    __shared__ alignas(16) int   itab[SPOS][GRP*NP][4];

    const int per  = SBLK / 8;               // 392
    const int bid  = blockIdx.x;
    const int sw   = (bid % 8) * per + (bid / 8);
    const int n0 = sw * SPOS;
    const int t = threadIdx.x;

    // load: 8 pos x (36 off-f4 + 18 msk-f4) = 432 float4 over 256 threads
    for (int u = t; u < SPOS * (NOFF/4); u += 256) {
        const int q = u / (NOFF/4), r = u % (NOFF/4);
        *(float4*)&loff[q][r*4] = *(const float4*)&omb[(size_t)(n0+q)*CH + r*4];
    }
    for (int u = t; u < SPOS * (NMSK/4); u += 256) {
        const int q = u / (NMSK/4), r = u % (NMSK/4);
        *(float4*)&lmsk[q][r*4] = *(const float4*)&omb[(size_t)(n0+q)*CH + NOFF + r*4];
    }
    __syncthreads();

    if (t < SPOS * GRP) {                    // 64 active lanes (was 32)
        const int q = t >> 3, g = t & 7;
        float* mm = &lmsk[q][g * NP];
        float mx = -1e30f;
        #pragma unroll
        for (int p = 0; p < NP; ++p) mx = fmaxf(mx, mm[p]);
        float sum = 0.0f;
        #pragma unroll
        for (int p = 0; p < NP; ++p) { const float e = __expf(mm[p] - mx); mm[p] = e; sum += e; }
        const float inv = 1.0f / sum;
        #pragma unroll
        for (int p = 0; p < NP; ++p) mm[p] *= inv;
    }
    __syncthreads();

    for (int u = t; u < SPOS * GRP * NP; u += 256) {
        const int q = u / (GRP*NP), j = u % (GRP*NP);
        const int g = j / NP, p = j % NP;
        const int n = n0 + q;
        const int hw = n % HW;
        const int h = hw / WDIM, w = hw % WDIM;
        const float ox = loff[q][g*18 + p*2 + 0];
        const float oy = loff[q][g*18 + p*2 + 1];
        const float m  = lmsk[q][g*NP + p];
        const float px = (float)(w + p/3) + ox;
        const float py = (float)(h + p%3) + oy;
        const float fx = floorf(px), fy = floorf(py);
        const float wx = px - fx, wy = py - fy;
        const int x0 = (int)fx, y0 = (int)fy;
        const int x1 = x0 + 1, y1 = y0 + 1;
        const float vx0 = (x0 >= 1 && x0 < 57) ? 1.0f : 0.0f;
        const float vx1 = (x1 >= 1 && x1 < 57) ? 1.0f : 0.0f;
        const float vy0 = (y0 >= 1 && y0 < 57) ? 1.0f : 0.0f;
        const float vy1 = (y1 >= 1 && y1 < 57) ? 1.0f : 0.0f;
        const int x0c = min(max(x0, 1), 56), x1c = min(max(x1, 1), 56);
        const int y0c = min(max(y0, 1), 56), y1c = min(max(y1, 1), 56);
        wtab[q][j][0] = m * (1.0f-wx) * (1.0f-wy) * vx0 * vy0;
        wtab[q][j][1] = m * wx        * (1.0f-wy) * vx1 * vy0;
        wtab[q][j][2] = m * (1.0f-wx) * wy        * vx0 * vy1;
        wtab[q][j][3] = m * wx        * wy        * vx1 * vy1;
        itab[q][j][0] = ((y0c-1)*WDIM + (x0c-1)) * CH;
        itab[q][j][1] = ((y0c-1)*WDIM + (x1c-1)) * CH;
        itab[q][j][2] = ((y1c-1)*WDIM + (x0c-1)) * CH;
        itab[q][j][3] = ((y1c-1)*WDIM + (x1c-1)) * CH;
    }
    __syncthreads();

    // gather: wave handles 2 positions, chains interleaved for 2x MLP
    const int wv = t >> 6, lane = t & 63;
    const int g = lane >> 3;
    const int q0 = wv * 2, q1 = q0 + 1;
    const int na = n0 + q0, nb = n0 + q1;
    const float* vba = v + (size_t)(na / HW) * HW * CH + lane * 4;
    const float* vbb = v + (size_t)(nb / HW) * HW * CH + lane * 4;
    float4 accA = {0.0f, 0.0f, 0.0f, 0.0f};
    float4 accB = {0.0f, 0.0f, 0.0f, 0.0f};
    #pragma unroll
    for (int p = 0; p < NP; ++p) {
        const int j = g*NP + p;
        const float4 wA = *(const float4*)&wtab[q0][j][0];
        const int4  iA = *(const int4*)&itab[q0][j][0];
        const float4 wB = *(const float4*)&wtab[q1][j][0];
        const int4  iB = *(const int4*)&itab[q1][j][0];
        const float4 a0 = *(const float4*)(vba + iA.x);
        const float4 a1 = *(const float4*)(vba + iA.y);
        const float4 a2 = *(const float4*)(vba + iA.z);
        const float4 a3 = *(const float4*)(vba + iA.w);
        const float4 b0 = *(const float4*)(vbb + iB.x);
        const float4 b1 = *(const float4*)(vbb + iB.y);
        const float4 b2 = *(const float4*)(vbb + iB.z);
        const float4 b3 = *(const float4*)(vbb + iB.w);
        accA.x += wA.x*a0.x + wA.y*a1.x + wA.z*a2.x + wA.w*a3.x;
        accA.y += wA.x*a0.y + wA.y*a1.y + wA.z*a2.y + wA.w*a3.y;
        accA.z += wA.x*a0.z + wA.y*a1.z + wA.z*a2.z + wA.w*a3.z;
        accA.w += wA.x*a0.w + wA.y*a1.w + wA.z*a2.w + wA.w*a3.w;
        accB.x += wB.x*b0.x + wB.y*b1.x + wB.z*b2.x + wB.w*b3.x;
        accB.y += wB.x*b0.y + wB.y*b1.y + wB.z*b2.y + wB.w*b3.y;
        accB.z += wB.x*b0.z + wB.y*b1.z + wB.z*b2.z + wB.w*b3.z;
        accB.w += wB.x*b0.w + wB.y*b1.w + wB.z*b2.w + wB.w*b3.w;
    }
    unsigned int hp0, lp0, hp1, lp1;
    split2(accA.x, accA.y, hp0, lp0);
    split2(accA.z, accA.w, hp1, lp1);
    *(uint2*)&sh[(size_t)na*CH + lane*4] = make_uint2(hp0, hp1);
    *(uint2*)&sl[(size_t)na*CH + lane*4] = make_uint2(lp0, lp1);
    split2(accB.x, accB.y, hp0, lp0);
    split2(accB.z, accB.w, hp1, lp1);
    *(uint2*)&sh[(size_t)nb*CH + lane*4] = make_uint2(hp0, hp1);
    *(uint2*)&sl[(size_t)nb*CH + lane*4] = make_uint2(lp0, lp1);
}

// ===================== FALLBACK KERNELS (round-5 verified) =====================
__global__ __launch_bounds__(256)
void xt_split_kernel(const float* __restrict__ x,
                     unsigned short* __restrict__ hi,
                     unsigned short* __restrict__ lo)
{
    __shared__ float lds[64][68];
    const int hw0 = blockIdx.x * 64;
    const int k0  = blockIdx.y * 64;
    const int b   = blockIdx.z;
    const int t = threadIdx.x;
    #pragma unroll
    for (int p = 0; p < 4; ++p) {
        const int kr = (t >> 4) + p * 16;
        const int hc = (t & 15) * 4;
        *(float4*)&lds[kr][hc] =
            *(const float4*)(x + ((size_t)b * CH + k0 + kr) * HW + hw0 + hc);
    }
    __syncthreads();
    const int ml = t >> 2;
    const int kc = (t & 3) * 16;
    unsigned int hbuf[8], lbuf[8];
    #pragma unroll
    for (int j = 0; j < 16; j += 2)
        split2(lds[kc + j][ml], lds[kc + j + 1][ml], hbuf[j >> 1], lbuf[j >> 1]);
    const size_t row = (size_t)(b * HW + hw0 + ml) * CH + k0 + kc;
    *(uint4*)&hi[row]     = *(uint4*)&hbuf[0];
    *(uint4*)&hi[row + 8] = *(uint4*)&hbuf[4];
    *(uint4*)&lo[row]     = *(uint4*)&lbuf[0];
    *(uint4*)&lo[row + 8] = *(uint4*)&lbuf[4];
}

__global__ __launch_bounds__(256)
void wt_split_kernel(const float* __restrict__ w,
                     unsigned short* __restrict__ hi,
                     unsigned short* __restrict__ lo)
{
    __shared__ float lds[64][68];
    const int kt = blockIdx.x * 64, nt = blockIdx.y * 64;
    const int t = threadIdx.x;
    #pragma unroll
    for (int p = 0; p < 4; ++p) {
        const int kr = (t >> 4) + p * 16, nc = (t & 15) * 4;
        *(float4*)&lds[kr][nc] = *(const float4*)(w + (size_t)(kt + kr) * CH + nt + nc);
    }
    __syncthreads();
    const int nl = t >> 2, kc = (t & 3) * 16;
    #pragma unroll
    for (int j = 0; j < 16; j += 2) {
        const float f0 = lds[kc + j][nl], f1 = lds[kc + j + 1][nl];
        unsigned int hp, lp;
        split2(f0, f1, hp, lp);
        *(unsigned int*)&hi[(size_t)(nt + nl) * CH + kt + kc + j] = hp;
        *(unsigned int*)&lo[(size_t)(nt + nl) * CH + kt + kc + j] = lp;
    }
}

__global__ __launch_bounds__(256)
void wt2_split_kernel(const float* __restrict__ w_off,
                      const float* __restrict__ w_mask,
                      const float* __restrict__ b_off,
                      const float* __restrict__ b_mask,
                      unsigned short* __restrict__ hi,
                      unsigned short* __restrict__ lo,
                      float* __restrict__ bcat)
{
    const int n = threadIdx.x;
    if (blockIdx.x == 0) {
        bcat[n] = (n < NOFF) ? b_off[n] : ((n < NTOT) ? b_mask[n - NOFF] : 0.0f);
    }
    const int k0 = blockIdx.x * 16;
    #pragma unroll
    for (int j = 0; j < 16; j += 2) {
        const int k = k0 + j;
        float f0 = 0.0f, f1 = 0.0f;
        if (n < NOFF) {
            f0 = w_off[(size_t)k * NOFF + n];
            f1 = w_off[(size_t)(k + 1) * NOFF + n];
        } else if (n < NTOT) {
            f0 = w_mask[(size_t)k * NMSK + (n - NOFF)];
            f1 = w_mask[(size_t)(k + 1) * NMSK + (n - NOFF)];
        }
        unsigned int hp, lp;
        split2(f0, f1, hp, lp);
        *(unsigned int*)&hi[(size_t)n * CH + k] = hp;
        *(unsigned int*)&lo[(size_t)n * CH + k] = lp;
    }
}

__global__ __launch_bounds__(256)
void gemm_in_mfma(const unsigned short* __restrict__ xhi,
                  const unsigned short* __restrict__ xlo,
                  const unsigned short* __restrict__ whi,
                  const unsigned short* __restrict__ wlo,
                  const float* __restrict__ bias,
                  float* __restrict__ v)
{
    const int m0 = blockIdx.x * 256;
    const int n0 = blockIdx.y * 64;
    const int t = threadIdx.x;
    const int lane = t & 63, wv = t >> 6;
    const int mblk = m0 + wv * 64;
    const int fm = lane & 15;
    const int q  = lane >> 4;

    f32x4 acc[4][4];
    const f32x4 zero = {0.0f, 0.0f, 0.0f, 0.0f};
    #pragma unroll
    for (int i = 0; i < 4; ++i)
        #pragma unroll
        for (int j = 0; j < 4; ++j) acc[i][j] = zero;

    const unsigned short *xrh[4], *xrl[4], *wrh[4], *wrl[4];
    #pragma unroll
    for (int mt = 0; mt < 4; ++mt) {
        xrh[mt] = xhi + (size_t)(mblk + mt*16 + fm) * CH + q * 8;
        xrl[mt] = xlo + (size_t)(mblk + mt*16 + fm) * CH + q * 8;
    }
    #pragma unroll
    for (int nt = 0; nt < 4; ++nt) {
        wrh[nt] = whi + (size_t)(n0 + nt*16 + fm) * CH + q * 8;
        wrl[nt] = wlo + (size_t)(n0 + nt*16 + fm) * CH + q * 8;
    }

    for (int k0 = 0; k0 < CH; k0 += 32) {
        s16x8 wh[4], wl[4], ah[4], al[4];
        #pragma unroll
        for (int nt = 0; nt < 4; ++nt) {
            wh[nt] = *(const s16x8*)(wrh[nt] + k0);
            wl[nt] = *(const s16x8*)(wrl[nt] + k0);
        }
        #pragma unroll
        for (int mt = 0; mt < 4; ++mt) {
            ah[mt] = *(const s16x8*)(xrh[mt] + k0);
            al[mt] = *(const s16x8*)(xrl[mt] + k0);
        }
        #pragma unroll
        for (int nt = 0; nt < 4; ++nt)
            #pragma unroll
            for (int mt = 0; mt < 4; ++mt) {
                acc[nt][mt] = __builtin_amdgcn_mfma_f32_16x16x32_bf16(wh[nt], ah[mt], acc[nt][mt], 0, 0, 0);
                acc[nt][mt] = __builtin_amdgcn_mfma_f32_16x16x32_bf16(wh[nt], al[mt], acc[nt][mt], 0, 0, 0);
                acc[nt][mt] = __builtin_amdgcn_mfma_f32_16x16x32_bf16(wl[nt], ah[mt], acc[nt][mt], 0, 0, 0);
            }
    }

    #pragma unroll
    for (int nt = 0; nt < 4; ++nt) {
        const float4 b4 = *(const float4*)&bias[n0 + nt*16 + q*4];
        #pragma unroll
        for (int mt = 0; mt < 4; ++mt) {
            f32x4 o = acc[nt][mt];
            o[0] += b4.x; o[1] += b4.y; o[2] += b4.z; o[3] += b4.w;
            *(f32x4*)&v[(size_t)(mblk + mt*16 + fm) * CH + n0 + nt*16 + q*4] = o;
        }
    }
}

__global__ __launch_bounds__(256)
void dw_ln_gelu_nhwc_split(const unsigned short* __restrict__ xhi,
                           const unsigned short* __restrict__ xlo,
                           const float* __restrict__ dw_w,
                           const float* __restrict__ dw_b,
                           const float* __restrict__ ln_g,
                           const float* __restrict__ ln_b,
                           unsigned short* __restrict__ fh,
                           unsigned short* __restrict__ fl)
{
    __shared__ float wt[NP][CH];
    __shared__ float lbias[CH], lgam[CH], lbet[CH];
    const int t = threadIdx.x;
    {
        const float* wp = dw_w + t * NP;
        #pragma unroll
        for (int p = 0; p < NP; ++p) wt[p][t] = wp[p];
        lbias[t] = dw_b[t]; lgam[t] = ln_g[t]; lbet[t] = ln_b[t];
    }
    __syncthreads();

    const int per  = DWBLK / 8;
    const int bid  = blockIdx.x;
    const int sw   = (bid & 7) * per + (bid >> 3);
    const int q    = t >> 6, lane = t & 63;
    const int n    = sw * POSB + q;
    const int b    = n / HW;
    const int hw   = n % HW;
    const int h    = hw / WDIM, w = hw % WDIM;
    const int c4   = lane * 4;
    const size_t base = (size_t)b * HW * CH + c4;

    float ax = 0.0f, ay = 0.0f, az = 0.0f, aw = 0.0f;
    #pragma unroll
    for (int p = 0; p < NP; ++p) {
        const int hh = h + p / 3 - 1;
        const int ww = w + p % 3 - 1;
        if ((unsigned)hh >= (unsigned)HDIM || (unsigned)ww >= (unsigned)WDIM)
            continue;
        const size_t idx = base + (size_t)(hh * WDIM + ww) * CH;
        const ushort4 uh = *(const ushort4*)(xhi + idx);
        const ushort4 ul = *(const ushort4*)(xlo + idx);
        const float4 wv = *(const float4*)&wt[p][c4];
        ax = fmaf(__uint_as_float((unsigned)uh.x << 16), wv.x,
             fmaf(__uint_as_float((unsigned)ul.x << 16), wv.x, ax));
        ay = fmaf(__uint_as_float((unsigned)uh.y << 16), wv.y,
             fmaf(__uint_as_float((unsigned)ul.y << 16), wv.y, ay));
        az = fmaf(__uint_as_float((unsigned)uh.z << 16), wv.z,
             fmaf(__uint_as_float((unsigned)ul.z << 16), wv.z, az));
        aw = fmaf(__uint_as_float((unsigned)uh.w << 16), wv.w,
             fmaf(__uint_as_float((unsigned)ul.w << 16), wv.w, aw));
    }
    {
        const float4 b4 = *(const float4*)&lbias[c4];
        ax += b4.x; ay += b4.y; az += b4.z; aw += b4.w;
    }
    float s1 = ax + ay + az + aw;
    float s2 = ax*ax + ay*ay + az*az + aw*aw;
    #pragma unroll
    for (int off = 32; off > 0; off >>= 1) {
        s1 += __shfl_xor(s1, off);
        s2 += __shfl_xor(s2, off);
    }
    const float mean = s1 * (1.0f / 256.0f);
    const float rstd = rsqrtf(s2 * (1.0f / 256.0f) - mean * mean + 1e-5f);
    const float4 g4 = *(const float4*)&lgam[c4];
    const float4 e4 = *(const float4*)&lbet[c4];
    const float x0 = (ax - mean) * rstd * g4.x + e4.x;
    const float x1 = (ay - mean) * rstd * g4.y + e4.y;
    const float x2 = (az - mean) * rstd * g4.z + e4.z;
    const float x3 = (aw - mean) * rstd * g4.w + e4.w;
    const float o0 = 0.5f * x0 * (1.0f + erff(x0 * 0.70710678118654752f));
    const float o1 = 0.5f * x1 * (1.0f + erff(x1 * 0.70710678118654752f));
    const float o2 = 0.5f * x2 * (1.0f + erff(x2 * 0.70710678118654752f));
    const float o3 = 0.5f * x3 * (1.0f + erff(x3 * 0.70710678118654752f));
    unsigned int hp0, lp0, hp1, lp1;
    split2(o0, o1, hp0, lp0);
    split2(o2, o3, hp1, lp1);
    *(uint2*)&fh[(size_t)n * CH + c4] = make_uint2(hp0, hp1);
    *(uint2*)&fl[(size_t)n * CH + c4] = make_uint2(lp0, lp1);
}

__global__ __launch_bounds__(256)
void sample_kernel_omb_split(const float* __restrict__ v,
                             const float* __restrict__ omb,
                             unsigned short* __restrict__ sh,
                             unsigned short* __restrict__ sl)
{
    __shared__ alignas(16) float loff[POSB][NOFF];
    __shared__ alignas(16) float lmsk[POSB][NMSK];
    __shared__ alignas(16) float wtab[POSB][GRP*NP][4];
    __shared__ alignas(16) int   itab[POSB][GRP*NP][4];

    const int per  = DWBLK / 8;
    const int bid  = blockIdx.x;
    const int sw   = (bid % 8) * per + (bid / 8);
    const int n0 = sw * POSB;
    const int t = threadIdx.x;

    if (t < POSB * (NOFF/4)) {
        const int q = t / (NOFF/4), r = t % (NOFF/4);
        *(float4*)&loff[q][r*4] = *(const float4*)&omb[(size_t)(n0+q)*CH + r*4];
    } else if (t < POSB * (NOFF/4) + POSB * (NMSK/4)) {
        const int u = t - POSB * (NOFF/4);
        const int q = u / (NMSK/4), r = u % (NMSK/4);
        *(float4*)&lmsk[q][r*4] = *(const float4*)&omb[(size_t)(n0+q)*CH + NOFF + r*4];
    }
    __syncthreads();

    if (t < POSB * GRP) {
        const int q = t >> 3, g = t & 7;
        float* mm = &lmsk[q][g * NP];
        float mx = -1e30f;
        #pragma unroll
        for (int p = 0; p < NP; ++p) mx = fmaxf(mx, mm[p]);
        float sum = 0.0f;
        #pragma unroll
        for (int p = 0; p < NP; ++p) { const float e = __expf(mm[p] - mx); mm[p] = e; sum += e; }
        const float inv = 1.0f / sum;
        #pragma unroll
        for (int p = 0; p < NP; ++p) mm[p] *= inv;
    }
    __syncthreads();

    for (int u = t; u < POSB * GRP * NP; u += 256) {
        const int q = u / (GRP*NP), j = u % (GRP*NP);
        const int g = j / NP, p = j % NP;
        const int n = n0 + q;
        const int hw = n % HW;
        const int h = hw / WDIM, w = hw % WDIM;
        const float ox = loff[q][g*18 + p*2 + 0];
        const float oy = loff[q][g*18 + p*2 + 1];
        const float m  = lmsk[q][g*NP + p];
        const float px = (float)(w + p/3) + ox;
        const float py = (float)(h + p%3) + oy;
        const float fx = floorf(px), fy = floorf(py);
        const float wx = px - fx, wy = py - fy;
        const int x0 = (int)fx, y0 = (int)fy;
        const int x1 = x0 + 1, y1 = y0 + 1;
        const float vx0 = (x0 >= 1 && x0 < 57) ? 1.0f : 0.0f;
        const float vx1 = (x1 >= 1 && x1 < 57) ? 1.0f : 0.0f;
        const float vy0 = (y0 >= 1 && y0 < 57) ? 1.0f : 0.0f;
        const float vy1 = (y1 >= 1 && y1 < 57) ? 1.0f : 0.0f;
        const int x0c = min(max(x0, 1), 56), x1c = min(max(x1, 1), 56);
        const int y0c = min(max(y0, 1), 56), y1c = min(max(y1, 1), 56);
        wtab[q][j][0] = m * (1.0f-wx) * (1.0f-wy) * vx0 * vy0;
        wtab[q][j][1] = m * wx        * (1.0f-wy) * vx1 * vy0;
        wtab[q][j][2] = m * (1.0f-wx) * wy        * vx0 * vy1;
        wtab[q][j][3] = m * wx        * wy        * vx1 * vy1;
        itab[q][j][0] = ((y0c-1)*WDIM + (x0c-1)) * CH;
        itab[q][j][1] = ((y0c-1)*WDIM + (x1c-1)) * CH;
        itab[q][j][2] = ((y1c-1)*WDIM + (x0c-1)) * CH;
        itab[q][j][3] = ((y1c-1)*WDIM + (x1c-1)) * CH;
    }
    __syncthreads();

    const int q = t >> 6, lane = t & 63;
    const int n = n0 + q;
    const int b = n / HW;
    const int g = lane >> 3;
    const float* vb = v + (size_t)b*HW*CH + lane*4;
    float4 acc = {0.0f, 0.0f, 0.0f, 0.0f};
    #pragma unroll
    for (int p = 0; p < NP; ++p) {
        const int j = g*NP + p;
        const float4 wv = *(const float4*)&wtab[q][j][0];
        const int4  iv = *(const int4*)&itab[q][j][0];
        const float4 c0 = *(const float4*)(vb + iv.x);
        const float4 c1 = *(const float4*)(vb + iv.y);
        const float4 c2 = *(const float4*)(vb + iv.z);
        const float4 c3 = *(const float4*)(vb + iv.w);
        acc.x += wv.x*c0.x + wv.y*c1.x + wv.z*c2.x + wv.w*c3.x;
        acc.y += wv.x*c0.y + wv.y*c1.y + wv.z*c2.y + wv.w*c3.y;
        acc.z += wv.x*c0.z + wv.y*c1.z + wv.z*c2.z + wv.w*c3.z;
        acc.w += wv.x*c0.w + wv.y*c1.w + wv.z*c2.w + wv.w*c3.w;
    }
    unsigned int hp0, lp0, hp1, lp1;
    split2(acc.x, acc.y, hp0, lp0);
    split2(acc.z, acc.w, hp1, lp1);
    *(uint2*)&sh[(size_t)n*CH + lane*4] = make_uint2(hp0, hp1);
    *(uint2*)&sl[(size_t)n*CH + lane*4] = make_uint2(lp0, lp1);
}

__global__ __launch_bounds__(256)
void gemm_out_bf16(const unsigned short* __restrict__ shp,
                   const unsigned short* __restrict__ slp,
                   const unsigned short* __restrict__ whi,
                   const unsigned short* __restrict__ wlo,
                   const float* __restrict__ bias,
                   const float* __restrict__ bn_g,
                   const float* __restrict__ bn_b,
                   const float* __restrict__ bn_mean,
                   const float* __restrict__ bn_var,
                   float* __restrict__ y)
{
    const int m0 = blockIdx.x * 256;
    const int n0 = blockIdx.y * 64;
    const int t = threadIdx.x;
    const int lane = t & 63, wv = t >> 6;
    const int mblk = m0 + wv * 64;
    const int fm = lane & 15;
    const int q  = lane >> 4;

    f32x4 acc[4][4];
    const f32x4 zero = {0.0f, 0.0f, 0.0f, 0.0f};
    #pragma unroll
    for (int i = 0; i < 4; ++i)
        #pragma unroll
        for (int j = 0; j < 4; ++j) acc[i][j] = zero;

    const unsigned short *xrh[4], *xrl[4], *wrh[4], *wrl[4];
    #pragma unroll
    for (int mt = 0; mt < 4; ++mt) {
        xrh[mt] = shp + (size_t)(mblk + mt*16 + fm) * CH + q * 8;
        xrl[mt] = slp + (size_t)(mblk + mt*16 + fm) * CH + q * 8;
    }
    #pragma unroll
    for (int nt = 0; nt < 4; ++nt) {
        wrh[nt] = whi + (size_t)(n0 + nt*16 + fm) * CH + q * 8;
        wrl[nt] = wlo + (size_t)(n0 + nt*16 + fm) * CH + q * 8;
    }

    for (int k0 = 0; k0 < CH; k0 += 32) {
        s16x8 wh[4], wl[4], ah[4], al[4];
        #pragma unroll
        for (int nt = 0; nt < 4; ++nt) {
            wh[nt] = *(const s16x8*)(wrh[nt] + k0);
            wl[nt] = *(const s16x8*)(wrl[nt] + k0);
        }
        #pragma unroll
        for (int mt = 0; mt < 4; ++mt) {
            ah[mt] = *(const s16x8*)(xrh[mt] + k0);
            al[mt] = *(const s16x8*)(xrl[mt] + k0);
        }
        #pragma unroll
        for (int nt = 0; nt < 4; ++nt)
            #pragma unroll
            for (int mt = 0; mt < 4; ++mt) {
                acc[nt][mt] = __builtin_amdgcn_mfma_f32_16x16x32_bf16(wh[nt], ah[mt], acc[nt][mt], 0, 0, 0);
                acc[nt][mt] = __builtin_amdgcn_mfma_f32_16x16x32_bf16(wh[nt], al[mt], acc[nt][mt], 0, 0, 0);
                acc[nt][mt] = __builtin_amdgcn_mfma_f32_16x16x32_bf16(wl[nt], ah[mt], acc[nt][mt], 0, 0, 0);
            }
    }

    #pragma unroll
    for (int nt = 0; nt < 4; ++nt) {
        #pragma unroll
        for (int r = 0; r < 4; ++r) {
            const int n = n0 + nt*16 + q*4 + r;
            const float sc = bn_g[n] * rsqrtf(bn_var[n] + 1e-5f);
            const float sb = bn_b[n] - bn_mean[n] * sc;
            const float bs = bias[n];
            #pragma unroll
            for (int mt = 0; mt < 4; ++mt) {
                const int mm = mblk + mt*16;
                const size_t base = (size_t)(mm / HW) * CH * HW + (mm % HW);
                float val = (acc[nt][mt][r] + bs) * sc + sb;
                y[base + (size_t)n * HW + fm] = val / (1.0f + expf(-val));
            }
        }
    }
}

extern "C" void kernel_launch(void* const* d_in, const int* in_sizes, int n_in,
                              void* d_out, int out_size, void* d_ws, size_t ws_size,
                              hipStream_t stream) {
    const float* x      = (const float*)d_in[0];
    const float* w_in   = (const float*)d_in[1];
    const float* b_in   = (const float*)d_in[2];
    const float* dw_w   = (const float*)d_in[3];
    const float* dw_b   = (const float*)d_in[4];
    const float* ln_g   = (const float*)d_in[5];
    const float* ln_b   = (const float*)d_in[6];
    const float* w_off  = (const float*)d_in[7];
    const float* b_off  = (const float*)d_in[8];
    const float* w_mask = (const float*)d_in[9];
    const float* b_mask = (const float*)d_in[10];
    const float* w_out  = (const float*)d_in[11];
    const float* b_out  = (const float*)d_in[12];
    const float* bn_g   = (const float*)d_in[13];
    const float* bn_b   = (const float*)d_in[14];
    const float* bn_mean= (const float*)d_in[15];
    const float* bn_var = (const float*)d_in[16];
    float* out = (float*)d_out;

    const size_t SZ = (size_t)MTOT * CH;                 // elements
    const size_t need_new =
        4 * SZ * sizeof(float)
        + 6 * (size_t)CH * CH * sizeof(unsigned short)
        + CH * sizeof(float);

    if (ws_size >= need_new) {
        // -------- main path: 5 dispatches --------
        float* ws = (float*)d_ws;
        float* v    = ws;                                          // SZ f32
        unsigned short* xt_hi = (unsigned short*)(v + SZ);         // SZ us
        unsigned short* xt_lo = xt_hi + SZ;                        // SZ us
        unsigned short* fh    = xt_lo + SZ;                        // SZ us
        unsigned short* fl    = fh + SZ;                           // SZ us
        float* omb  = (float*)(fl + SZ);                           // SZ f32
        unsigned short* wt_hi  = (unsigned short*)(omb + SZ);
        unsigned short* wt_lo  = wt_hi + CH * CH;
        unsigned short* wt2_hi = wt_lo + CH * CH;
        unsigned short* wt2_lo = wt2_hi + CH * CH;
        unsigned short* wt3_hi = wt2_lo + CH * CH;
        unsigned short* wt3_lo = wt3_hi + CH * CH;
        float* bcat = (float*)(wt3_lo + CH * CH);                  // 256 f32
        unsigned short* sh = xt_hi;
        unsigned short* sl = xt_lo;

        prep_kernel<<<dim3(XTBLK + 48), dim3(256), 0, stream>>>(
            x, xt_hi, xt_lo, w_out, wt_hi, wt_lo, w_in, wt3_hi, wt3_lo,
            w_off, w_mask, b_off, b_mask, wt2_hi, wt2_lo, bcat);
        dw2_ln_gelu_split<<<dim3(DW2BLK), dim3(256), 0, stream>>>(
            xt_hi, xt_lo, dw_w, dw_b, ln_g, ln_b, fh, fl);
        gemm_dual64<<<dim3(2 * NBLKG), dim3(256), 0, stream>>>(
            xt_hi, xt_lo, wt3_hi, wt3_lo, b_in, v,
            fh, fl, wt2_hi, wt2_lo, bcat, omb);
        sample8_omb_split<<<dim3(SBLK), dim3(256), 0, stream>>>(v, omb, sh, sl);
        gemm_out_64x128<<<dim3(NBLKG), dim3(256), 0, stream>>>(
            sh, sl, wt_hi, wt_lo, b_out, bn_g, bn_b, bn_mean, bn_var, out);
    } else {
        // -------- fallback: round-5 verified path --------
        float* ws = (float*)d_ws;
        float* v    = ws;
        unsigned short* xt_hi = (unsigned short*)(v + SZ);
        unsigned short* xt_lo = xt_hi + SZ;
        unsigned short* fh    = xt_lo + SZ;
        unsigned short* fl    = fh + SZ;
        float* omb  = (float*)(fl + SZ);
        unsigned short* wt_hi  = (unsigned short*)(omb + SZ);
        unsigned short* wt_lo  = wt_hi + CH * CH;
        unsigned short* wt2_hi = wt_lo + CH * CH;
        unsigned short* wt2_lo = wt2_hi + CH * CH;
        unsigned short* wt3_hi = wt2_lo + CH * CH;
        unsigned short* wt3_lo = wt3_hi + CH * CH;
        float* bcat = (float*)(wt3_lo + CH * CH);
        unsigned short* sh = xt_hi;
        unsigned short* sl = xt_lo;

        wt_split_kernel<<<dim3(4, 4), dim3(256), 0, stream>>>(w_out, wt_hi, wt_lo);
        wt_split_kernel<<<dim3(4, 4), dim3(256), 0, stream>>>(w_in, wt3_hi, wt3_lo);
        wt2_split_kernel<<<dim3(16), dim3(256), 0, stream>>>(
            w_off, w_mask, b_off, b_mask, wt2_hi, wt2_lo, bcat);
        xt_split_kernel<<<dim3(HW/64, CH/64, BATCH), dim3(256), 0, stream>>>(x, xt_hi, xt_lo);
        gemm_in_mfma<<<dim3(MTOT/256, CH/64), dim3(256), 0, stream>>>(
            xt_hi, xt_lo, wt3_hi, wt3_lo, b_in, v);
        dw_ln_gelu_nhwc_split<<<dim3(DWBLK), dim3(256), 0, stream>>>(
            xt_hi, xt_lo, dw_w, dw_b, ln_g, ln_b, fh, fl);
        gemm_in_mfma<<<dim3(MTOT/256, CH/64), dim3(256), 0, stream>>>(
            fh, fl, wt2_hi, wt2_lo, bcat, omb);
        sample_kernel_omb_split<<<dim3(DWBLK), dim3(256), 0, stream>>>(v, omb, sh, sl);
        gemm_out_bf16<<<dim3(MTOT/256, CH/64), dim3(256), 0, stream>>>(
            sh, sl, wt_hi, wt_lo, b_out, bn_g, bn_b, bn_mean, bn_var, out);
    }
}

// Round 15
// 218.535 us; speedup vs baseline: 1.0500x; 1.0500x over previous
//
#include <hip/hip_runtime.h>
#include <math.h>

// Problem constants
#define BATCH 8
#define CH    256
#define HDIM  56
#define WDIM  56
#define HW    (HDIM*WDIM)          // 3136
#define MTOT  (BATCH*HW)           // 25088
#define GRP   8
#define GC    32
#define NP    9                    // K*K
#define NOFF  (GRP*NP*2)           // 144
#define NMSK  (GRP*NP)             // 72
#define NTOT  (NOFF+NMSK)          // 216
#define POSB  4                    // positions per sample block
#define DWBLK (MTOT/POSB)          // 6272 (sample grid / fallback dw)
#define DW2BLK (MTOT/8)            // 3136 (main-path dw: 8 pos/block)
#define XTBLK (49*4*8)             // 1568 xt-split blocks
#define NBLKG ((MTOT/64)*2)        // 784: 392 m-tiles(64) x 2 n-tiles(128)

typedef float f32x4 __attribute__((ext_vector_type(4)));
typedef short s16x8 __attribute__((ext_vector_type(8)));

// split a,b into packed bf16 hi (truncation) and bf16 lo (exact remainder, truncated)
__device__ inline void split2(float a, float b, unsigned int& hp, unsigned int& lp)
{
    const unsigned int ua = __float_as_uint(a), ub = __float_as_uint(b);
    hp = (ub & 0xffff0000u) | (ua >> 16);
    const float ha = __uint_as_float(ua & 0xffff0000u);
    const float hb = __uint_as_float(ub & 0xffff0000u);
    const unsigned int la = __float_as_uint(a - ha), lb = __float_as_uint(b - hb);
    lp = (lb & 0xffff0000u) | (la >> 16);
}

// async global(16B/lane) -> LDS (wave-uniform base + lane*16)
__device__ __forceinline__ void gld_lds16(const unsigned short* g, unsigned short* l)
{
    __builtin_amdgcn_global_load_lds(
        (const __attribute__((address_space(1))) unsigned int*)g,
        (__attribute__((address_space(3))) unsigned int*)l, 16, 0, 0);
}

// ---------------------------------------------------------------------------
// 64m x 128n LDS-staged GEMM body (r10/r11-verified).
// ---------------------------------------------------------------------------
__device__ __forceinline__ void gemm64x128_body(
    const unsigned short* __restrict__ ahi,
    const unsigned short* __restrict__ alo,
    const unsigned short* __restrict__ whi,
    const unsigned short* __restrict__ wlo,
    unsigned short* sAh, unsigned short* sAl,
    unsigned short* sBh, unsigned short* sBl,
    int m0, int n0g, int t, f32x4 (&acc)[4][2])
{
    const int lane = t & 63, wv4 = t >> 6;
    const int wm = wv4 >> 1;
    const int wn = wv4 & 1;
    const int fm = lane & 15, q = lane >> 4;

    const int arow0 = t >> 2;
    const int asl0  = (t & 3) ^ ((arow0 >> 1) & 3);
    const int albase0 = wv4 * 512;             // shorts; wave-uniform
    int brow[2], bsl[2], blbase[2];
    #pragma unroll
    for (int i = 0; i < 2; ++i) {
        const int u = i * 256 + t;
        brow[i] = u >> 2;
        bsl[i] = (u & 3) ^ ((brow[i] >> 1) & 3);
        blbase[i] = i * 2048 + wv4 * 512;
    }

    for (int kk = 0; kk < 8; ++kk) {
        const int k0 = kk * 32;
        {
            const size_t ga = (size_t)(m0 + arow0) * CH + k0 + asl0 * 8;
            gld_lds16(ahi + ga, sAh + albase0);
            gld_lds16(alo + ga, sAl + albase0);
        }
        #pragma unroll
        for (int i = 0; i < 2; ++i) {
            const size_t gb = (size_t)(n0g + brow[i]) * CH + k0 + bsl[i] * 8;
            gld_lds16(whi + gb, sBh + blbase[i]);
            gld_lds16(wlo + gb, sBl + blbase[i]);
        }
        __syncthreads();

        s16x8 ah[2], al[2], wh[4], wl[4];
        #pragma unroll
        for (int i = 0; i < 2; ++i) {
            const int ar = wm * 32 + i * 16 + fm;
            const int as = (q ^ ((ar >> 1) & 3)) * 8;
            ah[i] = *(const s16x8*)&sAh[ar * 32 + as];
            al[i] = *(const s16x8*)&sAl[ar * 32 + as];
        }
        #pragma unroll
        for (int i = 0; i < 4; ++i) {
            const int br = wn * 64 + i * 16 + fm;
            const int bs = (q ^ ((br >> 1) & 3)) * 8;
            wh[i] = *(const s16x8*)&sBh[br * 32 + bs];
            wl[i] = *(const s16x8*)&sBl[br * 32 + bs];
        }
        #pragma unroll
        for (int nt = 0; nt < 4; ++nt)
            #pragma unroll
            for (int mt = 0; mt < 2; ++mt) {
                acc[nt][mt] = __builtin_amdgcn_mfma_f32_16x16x32_bf16(wh[nt], ah[mt], acc[nt][mt], 0, 0, 0);
                acc[nt][mt] = __builtin_amdgcn_mfma_f32_16x16x32_bf16(wh[nt], al[mt], acc[nt][mt], 0, 0, 0);
                acc[nt][mt] = __builtin_amdgcn_mfma_f32_16x16x32_bf16(wl[nt], ah[mt], acc[nt][mt], 0, 0, 0);
            }
        __syncthreads();
    }
}

// ---------------------------------------------------------------------------
// PREP: xt_split + wt_splits + wt2_split(+bcat), one dispatch. (r11-verified)
// ---------------------------------------------------------------------------
__global__ __launch_bounds__(256)
void prep_kernel(const float* __restrict__ x,
                 unsigned short* __restrict__ xt_hi,
                 unsigned short* __restrict__ xt_lo,
                 const float* __restrict__ w_out,
                 unsigned short* __restrict__ wt_hi,
                 unsigned short* __restrict__ wt_lo,
                 const float* __restrict__ w_in,
                 unsigned short* __restrict__ wt3_hi,
                 unsigned short* __restrict__ wt3_lo,
                 const float* __restrict__ w_off,
                 const float* __restrict__ w_mask,
                 const float* __restrict__ b_off,
                 const float* __restrict__ b_mask,
                 unsigned short* __restrict__ wt2_hi,
                 unsigned short* __restrict__ wt2_lo,
                 float* __restrict__ bcat)
{
    __shared__ float lds[64][68];
    const int bid = blockIdx.x;
    const int t = threadIdx.x;

    if (bid < XTBLK) {
        const int hw0 = (bid % 49) * 64;
        const int k0  = ((bid / 49) % 4) * 64;
        const int b   = bid / 196;
        #pragma unroll
        for (int p = 0; p < 4; ++p) {
            const int kr = (t >> 4) + p * 16;
            const int hc = (t & 15) * 4;
            *(float4*)&lds[kr][hc] =
                *(const float4*)(x + ((size_t)b * CH + k0 + kr) * HW + hw0 + hc);
        }
        __syncthreads();
        const int ml = t >> 2;
        const int kc = (t & 3) * 16;
        unsigned int hbuf[8], lbuf[8];
        #pragma unroll
        for (int j = 0; j < 16; j += 2)
            split2(lds[kc + j][ml], lds[kc + j + 1][ml], hbuf[j >> 1], lbuf[j >> 1]);
        const size_t row = (size_t)(b * HW + hw0 + ml) * CH + k0 + kc;
        *(uint4*)&xt_hi[row]     = *(uint4*)&hbuf[0];
        *(uint4*)&xt_hi[row + 8] = *(uint4*)&hbuf[4];
        *(uint4*)&xt_lo[row]     = *(uint4*)&lbuf[0];
        *(uint4*)&xt_lo[row + 8] = *(uint4*)&lbuf[4];
    } else if (bid < XTBLK + 32) {
        const int u = bid - XTBLK;
        const float* w = (u < 16) ? w_out : w_in;
        unsigned short* hi = (u < 16) ? wt_hi : wt3_hi;
        unsigned short* lo = (u < 16) ? wt_lo : wt3_lo;
        const int uu = u & 15;
        const int kt = (uu & 3) * 64, nt = (uu >> 2) * 64;
        #pragma unroll
        for (int p = 0; p < 4; ++p) {
            const int kr = (t >> 4) + p * 16, nc = (t & 15) * 4;
            *(float4*)&lds[kr][nc] = *(const float4*)(w + (size_t)(kt + kr) * CH + nt + nc);
        }
        __syncthreads();
        const int nl = t >> 2, kc = (t & 3) * 16;
        #pragma unroll
        for (int j = 0; j < 16; j += 2) {
            const float f0 = lds[kc + j][nl], f1 = lds[kc + j + 1][nl];
            unsigned int hp, lp;
            split2(f0, f1, hp, lp);
            *(unsigned int*)&hi[(size_t)(nt + nl) * CH + kt + kc + j] = hp;
            *(unsigned int*)&lo[(size_t)(nt + nl) * CH + kt + kc + j] = lp;
        }
    } else {
        const int u = bid - XTBLK - 32;    // 0..15
        const int n = t;
        if (u == 0) {
            bcat[n] = (n < NOFF) ? b_off[n] : ((n < NTOT) ? b_mask[n - NOFF] : 0.0f);
        }
        const int k0 = u * 16;
        #pragma unroll
        for (int j = 0; j < 16; j += 2) {
            const int k = k0 + j;
            float f0 = 0.0f, f1 = 0.0f;
            if (n < NOFF) {
                f0 = w_off[(size_t)k * NOFF + n];
                f1 = w_off[(size_t)(k + 1) * NOFF + n];
            } else if (n < NTOT) {
                f0 = w_mask[(size_t)k * NMSK + (n - NOFF)];
                f1 = w_mask[(size_t)(k + 1) * NMSK + (n - NOFF)];
            }
            unsigned int hp, lp;
            split2(f0, f1, hp, lp);
            *(unsigned int*)&wt2_hi[(size_t)n * CH + k] = hp;
            *(unsigned int*)&wt2_lo[(size_t)n * CH + k] = lp;
        }
    }
}

// ---------------------------------------------------------------------------
// dw, 2 positions per wave (r13-verified).
// ---------------------------------------------------------------------------
__global__ __launch_bounds__(256)
void dw2_ln_gelu_split(const unsigned short* __restrict__ xhi,
                       const unsigned short* __restrict__ xlo,
                       const float* __restrict__ dw_w,
                       const float* __restrict__ dw_b,
                       const float* __restrict__ ln_g,
                       const float* __restrict__ ln_b,
                       unsigned short* __restrict__ fh,
                       unsigned short* __restrict__ fl)
{
    __shared__ float wt[NP][CH];
    __shared__ float lbias[CH], lgam[CH], lbet[CH];
    const int t = threadIdx.x;
    {
        const float* wp = dw_w + t * NP;
        #pragma unroll
        for (int p = 0; p < NP; ++p) wt[p][t] = wp[p];
        lbias[t] = dw_b[t]; lgam[t] = ln_g[t]; lbet[t] = ln_b[t];
    }
    __syncthreads();

    const int per  = DW2BLK / 8;           // 392
    const int bid  = blockIdx.x;
    const int sw   = (bid & 7) * per + (bid >> 3);
    const int wv   = t >> 6, lane = t & 63;
    const int c4   = lane * 4;
    const float4 b4 = *(const float4*)&lbias[c4];
    const float4 g4 = *(const float4*)&lgam[c4];
    const float4 e4 = *(const float4*)&lbet[c4];

    #pragma unroll
    for (int i = 0; i < 2; ++i) {
        const int n  = sw * 8 + wv * 2 + i;
        const int b  = n / HW;
        const int hw = n % HW;
        const int h  = hw / WDIM, w = hw % WDIM;
        const size_t base = (size_t)b * HW * CH + c4;

        float ax = 0.0f, ay = 0.0f, az = 0.0f, aw = 0.0f;
        #pragma unroll
        for (int p = 0; p < NP; ++p) {
            const int hh = h + p / 3 - 1;
            const int ww = w + p % 3 - 1;
            if ((unsigned)hh >= (unsigned)HDIM || (unsigned)ww >= (unsigned)WDIM)
                continue;                   // wave-uniform branch (h,w per-wave)
            const size_t idx = base + (size_t)(hh * WDIM + ww) * CH;
            const ushort4 uh = *(const ushort4*)(xhi + idx);
            const ushort4 ul = *(const ushort4*)(xlo + idx);
            const float4 wv4 = *(const float4*)&wt[p][c4];
            ax = fmaf(__uint_as_float((unsigned)uh.x << 16), wv4.x,
                 fmaf(__uint_as_float((unsigned)ul.x << 16), wv4.x, ax));
            ay = fmaf(__uint_as_float((unsigned)uh.y << 16), wv4.y,
                 fmaf(__uint_as_float((unsigned)ul.y << 16), wv4.y, ay));
            az = fmaf(__uint_as_float((unsigned)uh.z << 16), wv4.z,
                 fmaf(__uint_as_float((unsigned)ul.z << 16), wv4.z, az));
            aw = fmaf(__uint_as_float((unsigned)uh.w << 16), wv4.w,
                 fmaf(__uint_as_float((unsigned)ul.w << 16), wv4.w, aw));
        }
        ax += b4.x; ay += b4.y; az += b4.z; aw += b4.w;

        float s1 = ax + ay + az + aw;
        float s2 = ax*ax + ay*ay + az*az + aw*aw;
        #pragma unroll
        for (int off = 32; off > 0; off >>= 1) {
            s1 += __shfl_xor(s1, off);
            s2 += __shfl_xor(s2, off);
        }
        const float mean = s1 * (1.0f / 256.0f);
        const float rstd = rsqrtf(s2 * (1.0f / 256.0f) - mean * mean + 1e-5f);

        const float x0 = (ax - mean) * rstd * g4.x + e4.x;
        const float x1 = (ay - mean) * rstd * g4.y + e4.y;
        const float x2 = (az - mean) * rstd * g4.z + e4.z;
        const float x3 = (aw - mean) * rstd * g4.w + e4.w;
        const float o0 = 0.5f * x0 * (1.0f + erff(x0 * 0.70710678118654752f));
        const float o1 = 0.5f * x1 * (1.0f + erff(x1 * 0.70710678118654752f));
        const float o2 = 0.5f * x2 * (1.0f + erff(x2 * 0.70710678118654752f));
        const float o3 = 0.5f * x3 * (1.0f + erff(x3 * 0.70710678118654752f));

        unsigned int hp0, lp0, hp1, lp1;
        split2(o0, o1, hp0, lp0);
        split2(o2, o3, hp1, lp1);
        *(uint2*)&fh[(size_t)n * CH + c4] = make_uint2(hp0, hp1);
        *(uint2*)&fl[(size_t)n * CH + c4] = make_uint2(lp0, lp1);
    }
}

// ---------------------------------------------------------------------------
// DUAL GEMM after dw (r12-verified).
// ---------------------------------------------------------------------------
__global__ __launch_bounds__(256)
void gemm_dual64(const unsigned short* __restrict__ ahi1,
                 const unsigned short* __restrict__ alo1,
                 const unsigned short* __restrict__ whi1,
                 const unsigned short* __restrict__ wlo1,
                 const float* __restrict__ bias1,
                 float* __restrict__ out1,
                 const unsigned short* __restrict__ ahi2,
                 const unsigned short* __restrict__ alo2,
                 const unsigned short* __restrict__ whi2,
                 const unsigned short* __restrict__ wlo2,
                 const float* __restrict__ bias2,
                 float* __restrict__ out2)
{
    __shared__ unsigned short sAh[64*32], sAl[64*32], sBh[128*32], sBl[128*32];

    const int half = blockIdx.x >= NBLKG;
    const int lbid = blockIdx.x - (half ? NBLKG : 0);
    const unsigned short* ahi = half ? ahi2 : ahi1;
    const unsigned short* alo = half ? alo2 : alo1;
    const unsigned short* whi = half ? whi2 : whi1;
    const unsigned short* wlo = half ? wlo2 : wlo1;
    const float* bias = half ? bias2 : bias1;
    float* out = half ? out2 : out1;

    const int sw = (lbid & 7) * (NBLKG / 8) + (lbid >> 3);   // bijective 784=8*98
    const int m0  = (sw >> 1) * 64;
    const int n0g = (sw & 1) * 128;
    const int t = threadIdx.x;
    const int lane = t & 63, wv4 = t >> 6;
    const int wm = wv4 >> 1, wn = wv4 & 1;
    const int fm = lane & 15, q = lane >> 4;

    f32x4 acc[4][2];
    const f32x4 zero = {0.0f, 0.0f, 0.0f, 0.0f};
    #pragma unroll
    for (int i = 0; i < 4; ++i)
        #pragma unroll
        for (int j = 0; j < 2; ++j) acc[i][j] = zero;

    gemm64x128_body(ahi, alo, whi, wlo, sAh, sAl, sBh, sBl, m0, n0g, t, acc);

    #pragma unroll
    for (int nt = 0; nt < 4; ++nt) {
        const int n = n0g + wn*64 + nt*16 + q*4;
        const float4 b4 = *(const float4*)&bias[n];
        #pragma unroll
        for (int mt = 0; mt < 2; ++mt) {
            const int mm = m0 + wm*32 + mt*16 + fm;
            f32x4 o = acc[nt][mt];
            o[0] += b4.x; o[1] += b4.y; o[2] += b4.z; o[3] += b4.w;
            *(f32x4*)&out[(size_t)mm * CH + n] = o;
        }
    }
}

// ---------------------------------------------------------------------------
// Output GEMM, 64m x 128n tiles (r10-verified): BN+SiLU NCHW epilogue.
// ---------------------------------------------------------------------------
__global__ __launch_bounds__(256)
void gemm_out_64x128(const unsigned short* __restrict__ ahi,
                     const unsigned short* __restrict__ alo,
                     const unsigned short* __restrict__ whi,
                     const unsigned short* __restrict__ wlo,
                     const float* __restrict__ bias,
                     const float* __restrict__ bn_g,
                     const float* __restrict__ bn_b,
                     const float* __restrict__ bn_mean,
                     const float* __restrict__ bn_var,
                     float* __restrict__ y)                  // [B,256,3136]
{
    __shared__ unsigned short sAh[64*32], sAl[64*32], sBh[128*32], sBl[128*32];

    const int sw = (blockIdx.x & 7) * (NBLKG / 8) + (blockIdx.x >> 3);
    const int m0  = (sw >> 1) * 64;
    const int n0g = (sw & 1) * 128;
    const int t = threadIdx.x;
    const int lane = t & 63, wv4 = t >> 6;
    const int wm = wv4 >> 1, wn = wv4 & 1;
    const int fm = lane & 15, q = lane >> 4;

    f32x4 acc[4][2];
    const f32x4 zero = {0.0f, 0.0f, 0.0f, 0.0f};
    #pragma unroll
    for (int i = 0; i < 4; ++i)
        #pragma unroll
        for (int j = 0; j < 2; ++j) acc[i][j] = zero;

    gemm64x128_body(ahi, alo, whi, wlo, sAh, sAl, sBh, sBl, m0, n0g, t, acc);

    #pragma unroll
    for (int nt = 0; nt < 4; ++nt) {
        #pragma unroll
        for (int r = 0; r < 4; ++r) {
            const int n = n0g + wn*64 + nt*16 + q*4 + r;
            const float sc = bn_g[n] * rsqrtf(bn_var[n] + 1e-5f);
            const float sb = bn_b[n] - bn_mean[n] * sc;
            const float bs = bias[n];
            #pragma unroll
            for (int mt = 0; mt < 2; ++mt) {
                const int mm = m0 + wm*32 + mt*16 + fm;
                const int bimg = mm / HW, hw = mm % HW;
                float val = (acc[nt][mt][r] + bs) * sc + sb;
                y[(size_t)bimg * CH * HW + (size_t)n * HW + hw] = val / (1.0f + expf(-val));
            }
        }
    }
}

// ---------------------------------------------------------------------------
// Sampling (r13-verified best: POSB=4, 1 pos/wave, 56 VGPR, 34% occupancy).
// r14 lesson: 2-pos/wave doubled VGPR to 100, halved occupancy, -26% perf.
// ---------------------------------------------------------------------------
__global__ __launch_bounds__(256)
void sample_kernel_omb_split(const float* __restrict__ v,
                             const float* __restrict__ omb,
                             unsigned short* __restrict__ sh,  // [MTOT][256]
                             unsigned short* __restrict__ sl)  // [MTOT][256]
{
    __shared__ alignas(16) float loff[POSB][NOFF];
    __shared__ alignas(16) float lmsk[POSB][NMSK];
    __shared__ alignas(16) float wtab[POSB][GRP*NP][4];
    __shared__ alignas(16) int   itab[POSB][GRP*NP][4];

    const int per  = DWBLK / 8;              // 784
    const int bid  = blockIdx.x;
    const int sw   = (bid % 8) * per + (bid / 8);
    const int n0 = sw * POSB;
    const int t = threadIdx.x;

    if (t < POSB * (NOFF/4)) {
        const int q = t / (NOFF/4), r = t % (NOFF/4);
        *(float4*)&loff[q][r*4] = *(const float4*)&omb[(size_t)(n0+q)*CH + r*4];
    } else if (t < POSB * (NOFF/4) + POSB * (NMSK/4)) {
        const int u = t - POSB * (NOFF/4);
        const int q = u / (NMSK/4), r = u % (NMSK/4);
        *(float4*)&lmsk[q][r*4] = *(const float4*)&omb[(size_t)(n0+q)*CH + NOFF + r*4];
    }
    __syncthreads();

    if (t < POSB * GRP) {
        const int q = t >> 3, g = t & 7;
        float* mm = &lmsk[q][g * NP];
        float mx = -1e30f;
        #pragma unroll
        for (int p = 0; p < NP; ++p) mx = fmaxf(mx, mm[p]);
        float sum = 0.0f;
        #pragma unroll
        for (int p = 0; p < NP; ++p) { const float e = __expf(mm[p] - mx); mm[p] = e; sum += e; }
        const float inv = 1.0f / sum;
        #pragma unroll
        for (int p = 0; p < NP; ++p) mm[p] *= inv;
    }
    __syncthreads();

    for (int u = t; u < POSB * GRP * NP; u += 256) {
        const int q = u / (GRP*NP), j = u % (GRP*NP);
        const int g = j / NP, p = j % NP;
        const int n = n0 + q;
        const int hw = n % HW;
        const int h = hw / WDIM, w = hw % WDIM;
        const float ox = loff[q][g*18 + p*2 + 0];
        const float oy = loff[q][g*18 + p*2 + 1];
        const float m  = lmsk[q][g*NP + p];
        const float px = (float)(w + p/3) + ox;
        const float py = (float)(h + p%3) + oy;
        const float fx = floorf(px), fy = floorf(py);
        const float wx = px - fx, wy = py - fy;
        const int x0 = (int)fx, y0 = (int)fy;
        const int x1 = x0 + 1, y1 = y0 + 1;
        const float vx0 = (x0 >= 1 && x0 < 57) ? 1.0f : 0.0f;
        const float vx1 = (x1 >= 1 && x1 < 57) ? 1.0f : 0.0f;
        const float vy0 = (y0 >= 1 && y0 < 57) ? 1.0f : 0.0f;
        const float vy1 = (y1 >= 1 && y1 < 57) ? 1.0f : 0.0f;
        const int x0c = min(max(x0, 1), 56), x1c = min(max(x1, 1), 56);
        const int y0c = min(max(y0, 1), 56), y1c = min(max(y1, 1), 56);
        wtab[q][j][0] = m * (1.0f-wx) * (1.0f-wy) * vx0 * vy0;
        wtab[q][j][1] = m * wx        * (1.0f-wy) * vx1 * vy0;
        wtab[q][j][2] = m * (1.0f-wx) * wy        * vx0 * vy1;
        wtab[q][j][3] = m * wx        * wy        * vx1 * vy1;
        itab[q][j][0] = ((y0c-1)*WDIM + (x0c-1)) * CH;
        itab[q][j][1] = ((y0c-1)*WDIM + (x1c-1)) * CH;
        itab[q][j][2] = ((y1c-1)*WDIM + (x0c-1)) * CH;
        itab[q][j][3] = ((y1c-1)*WDIM + (x1c-1)) * CH;
    }
    __syncthreads();

    const int q = t >> 6, lane = t & 63;
    const int n = n0 + q;
    const int b = n / HW;
    const int g = lane >> 3;
    const float* vb = v + (size_t)b*HW*CH + lane*4;
    float4 acc = {0.0f, 0.0f, 0.0f, 0.0f};
    #pragma unroll
    for (int p = 0; p < NP; ++p) {
        const int j = g*NP + p;
        const float4 wv = *(const float4*)&wtab[q][j][0];
        const int4  iv = *(const int4*)&itab[q][j][0];
        const float4 c0 = *(const float4*)(vb + iv.x);
        const float4 c1 = *(const float4*)(vb + iv.y);
        const float4 c2 = *(const float4*)(vb + iv.z);
        const float4 c3 = *(const float4*)(vb + iv.w);
        acc.x += wv.x*c0.x + wv.y*c1.x + wv.z*c2.x + wv.w*c3.x;
        acc.y += wv.x*c0.y + wv.y*c1.y + wv.z*c2.y + wv.w*c3.y;
        acc.z += wv.x*c0.z + wv.y*c1.z + wv.z*c2.z + wv.w*c3.z;
        acc.w += wv.x*c0.w + wv.y*c1.w + wv.z*c2.w + wv.w*c3.w;
    }
    unsigned int hp0, lp0, hp1, lp1;
    split2(acc.x, acc.y, hp0, lp0);
    split2(acc.z, acc.w, hp1, lp1);
    *(uint2*)&sh[(size_t)n*CH + lane*4] = make_uint2(hp0, hp1);
    *(uint2*)&sl[(size_t)n*CH + lane*4] = make_uint2(lp0, lp1);
}

// ===================== FALLBACK KERNELS (round-5 verified) =====================
__global__ __launch_bounds__(256)
void xt_split_kernel(const float* __restrict__ x,
                     unsigned short* __restrict__ hi,
                     unsigned short* __restrict__ lo)
{
    __shared__ float lds[64][68];
    const int hw0 = blockIdx.x * 64;
    const int k0  = blockIdx.y * 64;
    const int b   = blockIdx.z;
    const int t = threadIdx.x;
    #pragma unroll
    for (int p = 0; p < 4; ++p) {
        const int kr = (t >> 4) + p * 16;
        const int hc = (t & 15) * 4;
        *(float4*)&lds[kr][hc] =
            *(const float4*)(x + ((size_t)b * CH + k0 + kr) * HW + hw0 + hc);
    }
    __syncthreads();
    const int ml = t >> 2;
    const int kc = (t & 3) * 16;
    unsigned int hbuf[8], lbuf[8];
    #pragma unroll
    for (int j = 0; j < 16; j += 2)
        split2(lds[kc + j][ml], lds[kc + j + 1][ml], hbuf[j >> 1], lbuf[j >> 1]);
    const size_t row = (size_t)(b * HW + hw0 + ml) * CH + k0 + kc;
    *(uint4*)&hi[row]     = *(uint4*)&hbuf[0];
    *(uint4*)&hi[row + 8] = *(uint4*)&hbuf[4];
    *(uint4*)&lo[row]     = *(uint4*)&lbuf[0];
    *(uint4*)&lo[row + 8] = *(uint4*)&lbuf[4];
}

__global__ __launch_bounds__(256)
void wt_split_kernel(const float* __restrict__ w,
                     unsigned short* __restrict__ hi,
                     unsigned short* __restrict__ lo)
{
    __shared__ float lds[64][68];
    const int kt = blockIdx.x * 64, nt = blockIdx.y * 64;
    const int t = threadIdx.x;
    #pragma unroll
    for (int p = 0; p < 4; ++p) {
        const int kr = (t >> 4) + p * 16, nc = (t & 15) * 4;
        *(float4*)&lds[kr][nc] = *(const float4*)(w + (size_t)(kt + kr) * CH + nt + nc);
    }
    __syncthreads();
    const int nl = t >> 2, kc = (t & 3) * 16;
    #pragma unroll
    for (int j = 0; j < 16; j += 2) {
        const float f0 = lds[kc + j][nl], f1 = lds[kc + j + 1][nl];
        unsigned int hp, lp;
        split2(f0, f1, hp, lp);
        *(unsigned int*)&hi[(size_t)(nt + nl) * CH + kt + kc + j] = hp;
        *(unsigned int*)&lo[(size_t)(nt + nl) * CH + kt + kc + j] = lp;
    }
}

__global__ __launch_bounds__(256)
void wt2_split_kernel(const float* __restrict__ w_off,
                      const float* __restrict__ w_mask,
                      const float* __restrict__ b_off,
                      const float* __restrict__ b_mask,
                      unsigned short* __restrict__ hi,
                      unsigned short* __restrict__ lo,
                      float* __restrict__ bcat)
{
    const int n = threadIdx.x;
    if (blockIdx.x == 0) {
        bcat[n] = (n < NOFF) ? b_off[n] : ((n < NTOT) ? b_mask[n - NOFF] : 0.0f);
    }
    const int k0 = blockIdx.x * 16;
    #pragma unroll
    for (int j = 0; j < 16; j += 2) {
        const int k = k0 + j;
        float f0 = 0.0f, f1 = 0.0f;
        if (n < NOFF) {
            f0 = w_off[(size_t)k * NOFF + n];
            f1 = w_off[(size_t)(k + 1) * NOFF + n];
        } else if (n < NTOT) {
            f0 = w_mask[(size_t)k * NMSK + (n - NOFF)];
            f1 = w_mask[(size_t)(k + 1) * NMSK + (n - NOFF)];
        }
        unsigned int hp, lp;
        split2(f0, f1, hp, lp);
        *(unsigned int*)&hi[(size_t)n * CH + k] = hp;
        *(unsigned int*)&lo[(size_t)n * CH + k] = lp;
    }
}

__global__ __launch_bounds__(256)
void gemm_in_mfma(const unsigned short* __restrict__ xhi,
                  const unsigned short* __restrict__ xlo,
                  const unsigned short* __restrict__ whi,
                  const unsigned short* __restrict__ wlo,
                  const float* __restrict__ bias,
                  float* __restrict__ v)
{
    const int m0 = blockIdx.x * 256;
    const int n0 = blockIdx.y * 64;
    const int t = threadIdx.x;
    const int lane = t & 63, wv = t >> 6;
    const int mblk = m0 + wv * 64;
    const int fm = lane & 15;
    const int q  = lane >> 4;

    f32x4 acc[4][4];
    const f32x4 zero = {0.0f, 0.0f, 0.0f, 0.0f};
    #pragma unroll
    for (int i = 0; i < 4; ++i)
        #pragma unroll
        for (int j = 0; j < 4; ++j) acc[i][j] = zero;

    const unsigned short *xrh[4], *xrl[4], *wrh[4], *wrl[4];
    #pragma unroll
    for (int mt = 0; mt < 4; ++mt) {
        xrh[mt] = xhi + (size_t)(mblk + mt*16 + fm) * CH + q * 8;
        xrl[mt] = xlo + (size_t)(mblk + mt*16 + fm) * CH + q * 8;
    }
    #pragma unroll
    for (int nt = 0; nt < 4; ++nt) {
        wrh[nt] = whi + (size_t)(n0 + nt*16 + fm) * CH + q * 8;
        wrl[nt] = wlo + (size_t)(n0 + nt*16 + fm) * CH + q * 8;
    }

    for (int k0 = 0; k0 < CH; k0 += 32) {
        s16x8 wh[4], wl[4], ah[4], al[4];
        #pragma unroll
        for (int nt = 0; nt < 4; ++nt) {
            wh[nt] = *(const s16x8*)(wrh[nt] + k0);
            wl[nt] = *(const s16x8*)(wrl[nt] + k0);
        }
        #pragma unroll
        for (int mt = 0; mt < 4; ++mt) {
            ah[mt] = *(const s16x8*)(xrh[mt] + k0);
            al[mt] = *(const s16x8*)(xrl[mt] + k0);
        }
        #pragma unroll
        for (int nt = 0; nt < 4; ++nt)
            #pragma unroll
            for (int mt = 0; mt < 4; ++mt) {
                acc[nt][mt] = __builtin_amdgcn_mfma_f32_16x16x32_bf16(wh[nt], ah[mt], acc[nt][mt], 0, 0, 0);
                acc[nt][mt] = __builtin_amdgcn_mfma_f32_16x16x32_bf16(wh[nt], al[mt], acc[nt][mt], 0, 0, 0);
                acc[nt][mt] = __builtin_amdgcn_mfma_f32_16x16x32_bf16(wl[nt], ah[mt], acc[nt][mt], 0, 0, 0);
            }
    }

    #pragma unroll
    for (int nt = 0; nt < 4; ++nt) {
        const float4 b4 = *(const float4*)&bias[n0 + nt*16 + q*4];
        #pragma unroll
        for (int mt = 0; mt < 4; ++mt) {
            f32x4 o = acc[nt][mt];
            o[0] += b4.x; o[1] += b4.y; o[2] += b4.z; o[3] += b4.w;
            *(f32x4*)&v[(size_t)(mblk + mt*16 + fm) * CH + n0 + nt*16 + q*4] = o;
        }
    }
}

__global__ __launch_bounds__(256)
void dw_ln_gelu_nhwc_split(const unsigned short* __restrict__ xhi,
                           const unsigned short* __restrict__ xlo,
                           const float* __restrict__ dw_w,
                           const float* __restrict__ dw_b,
                           const float* __restrict__ ln_g,
                           const float* __restrict__ ln_b,
                           unsigned short* __restrict__ fh,
                           unsigned short* __restrict__ fl)
{
    __shared__ float wt[NP][CH];
    __shared__ float lbias[CH], lgam[CH], lbet[CH];
    const int t = threadIdx.x;
    {
        const float* wp = dw_w + t * NP;
        #pragma unroll
        for (int p = 0; p < NP; ++p) wt[p][t] = wp[p];
        lbias[t] = dw_b[t]; lgam[t] = ln_g[t]; lbet[t] = ln_b[t];
    }
    __syncthreads();

    const int per  = DWBLK / 8;
    const int bid  = blockIdx.x;
    const int sw   = (bid & 7) * per + (bid >> 3);
    const int q    = t >> 6, lane = t & 63;
    const int n    = sw * POSB + q;
    const int b    = n / HW;
    const int hw   = n % HW;
    const int h    = hw / WDIM, w = hw % WDIM;
    const int c4   = lane * 4;
    const size_t base = (size_t)b * HW * CH + c4;

    float ax = 0.0f, ay = 0.0f, az = 0.0f, aw = 0.0f;
    #pragma unroll
    for (int p = 0; p < NP; ++p) {
        const int hh = h + p / 3 - 1;
        const int ww = w + p % 3 - 1;
        if ((unsigned)hh >= (unsigned)HDIM || (unsigned)ww >= (unsigned)WDIM)
            continue;
        const size_t idx = base + (size_t)(hh * WDIM + ww) * CH;
        const ushort4 uh = *(const ushort4*)(xhi + idx);
        const ushort4 ul = *(const ushort4*)(xlo + idx);
        const float4 wv = *(const float4*)&wt[p][c4];
        ax = fmaf(__uint_as_float((unsigned)uh.x << 16), wv.x,
             fmaf(__uint_as_float((unsigned)ul.x << 16), wv.x, ax));
        ay = fmaf(__uint_as_float((unsigned)uh.y << 16), wv.y,
             fmaf(__uint_as_float((unsigned)ul.y << 16), wv.y, ay));
        az = fmaf(__uint_as_float((unsigned)uh.z << 16), wv.z,
             fmaf(__uint_as_float((unsigned)ul.z << 16), wv.z, az));
        aw = fmaf(__uint_as_float((unsigned)uh.w << 16), wv.w,
             fmaf(__uint_as_float((unsigned)ul.w << 16), wv.w, aw));
    }
    {
        const float4 b4 = *(const float4*)&lbias[c4];
        ax += b4.x; ay += b4.y; az += b4.z; aw += b4.w;
    }
    float s1 = ax + ay + az + aw;
    float s2 = ax*ax + ay*ay + az*az + aw*aw;
    #pragma unroll
    for (int off = 32; off > 0; off >>= 1) {
        s1 += __shfl_xor(s1, off);
        s2 += __shfl_xor(s2, off);
    }
    const float mean = s1 * (1.0f / 256.0f);
    const float rstd = rsqrtf(s2 * (1.0f / 256.0f) - mean * mean + 1e-5f);
    const float4 g4 = *(const float4*)&lgam[c4];
    const float4 e4 = *(const float4*)&lbet[c4];
    const float x0 = (ax - mean) * rstd * g4.x + e4.x;
    const float x1 = (ay - mean) * rstd * g4.y + e4.y;
    const float x2 = (az - mean) * rstd * g4.z + e4.z;
    const float x3 = (aw - mean) * rstd * g4.w + e4.w;
    const float o0 = 0.5f * x0 * (1.0f + erff(x0 * 0.70710678118654752f));
    const float o1 = 0.5f * x1 * (1.0f + erff(x1 * 0.70710678118654752f));
    const float o2 = 0.5f * x2 * (1.0f + erff(x2 * 0.70710678118654752f));
    const float o3 = 0.5f * x3 * (1.0f + erff(x3 * 0.70710678118654752f));
    unsigned int hp0, lp0, hp1, lp1;
    split2(o0, o1, hp0, lp0);
    split2(o2, o3, hp1, lp1);
    *(uint2*)&fh[(size_t)n * CH + c4] = make_uint2(hp0, hp1);
    *(uint2*)&fl[(size_t)n * CH + c4] = make_uint2(lp0, lp1);
}

__global__ __launch_bounds__(256)
void gemm_out_bf16(const unsigned short* __restrict__ shp,
                   const unsigned short* __restrict__ slp,
                   const unsigned short* __restrict__ whi,
                   const unsigned short* __restrict__ wlo,
                   const float* __restrict__ bias,
                   const float* __restrict__ bn_g,
                   const float* __restrict__ bn_b,
                   const float* __restrict__ bn_mean,
                   const float* __restrict__ bn_var,
                   float* __restrict__ y)
{
    const int m0 = blockIdx.x * 256;
    const int n0 = blockIdx.y * 64;
    const int t = threadIdx.x;
    const int lane = t & 63, wv = t >> 6;
    const int mblk = m0 + wv * 64;
    const int fm = lane & 15;
    const int q  = lane >> 4;

    f32x4 acc[4][4];
    const f32x4 zero = {0.0f, 0.0f, 0.0f, 0.0f};
    #pragma unroll
    for (int i = 0; i < 4; ++i)
        #pragma unroll
        for (int j = 0; j < 4; ++j) acc[i][j] = zero;

    const unsigned short *xrh[4], *xrl[4], *wrh[4], *wrl[4];
    #pragma unroll
    for (int mt = 0; mt < 4; ++mt) {
        xrh[mt] = shp + (size_t)(mblk + mt*16 + fm) * CH + q * 8;
        xrl[mt] = slp + (size_t)(mblk + mt*16 + fm) * CH + q * 8;
    }
    #pragma unroll
    for (int nt = 0; nt < 4; ++nt) {
        wrh[nt] = whi + (size_t)(n0 + nt*16 + fm) * CH + q * 8;
        wrl[nt] = wlo + (size_t)(n0 + nt*16 + fm) * CH + q * 8;
    }

    for (int k0 = 0; k0 < CH; k0 += 32) {
        s16x8 wh[4], wl[4], ah[4], al[4];
        #pragma unroll
        for (int nt = 0; nt < 4; ++nt) {
            wh[nt] = *(const s16x8*)(wrh[nt] + k0);
            wl[nt] = *(const s16x8*)(wrl[nt] + k0);
        }
        #pragma unroll
        for (int mt = 0; mt < 4; ++mt) {
            ah[mt] = *(const s16x8*)(xrh[mt] + k0);
            al[mt] = *(const s16x8*)(xrl[mt] + k0);
        }
        #pragma unroll
        for (int nt = 0; nt < 4; ++nt)
            #pragma unroll
            for (int mt = 0; mt < 4; ++mt) {
                acc[nt][mt] = __builtin_amdgcn_mfma_f32_16x16x32_bf16(wh[nt], ah[mt], acc[nt][mt], 0, 0, 0);
                acc[nt][mt] = __builtin_amdgcn_mfma_f32_16x16x32_bf16(wh[nt], al[mt], acc[nt][mt], 0, 0, 0);
                acc[nt][mt] = __builtin_amdgcn_mfma_f32_16x16x32_bf16(wl[nt], ah[mt], acc[nt][mt], 0, 0, 0);
            }
    }

    #pragma unroll
    for (int nt = 0; nt < 4; ++nt) {
        #pragma unroll
        for (int r = 0; r < 4; ++r) {
            const int n = n0 + nt*16 + q*4 + r;
            const float sc = bn_g[n] * rsqrtf(bn_var[n] + 1e-5f);
            const float sb = bn_b[n] - bn_mean[n] * sc;
            const float bs = bias[n];
            #pragma unroll
            for (int mt = 0; mt < 4; ++mt) {
                const int mm = mblk + mt*16;
                const size_t base = (size_t)(mm / HW) * CH * HW + (mm % HW);
                float val = (acc[nt][mt][r] + bs) * sc + sb;
                y[base + (size_t)n * HW + fm] = val / (1.0f + expf(-val));
            }
        }
    }
}

extern "C" void kernel_launch(void* const* d_in, const int* in_sizes, int n_in,
                              void* d_out, int out_size, void* d_ws, size_t ws_size,
                              hipStream_t stream) {
    const float* x      = (const float*)d_in[0];
    const float* w_in   = (const float*)d_in[1];
    const float* b_in   = (const float*)d_in[2];
    const float* dw_w   = (const float*)d_in[3];
    const float* dw_b   = (const float*)d_in[4];
    const float* ln_g   = (const float*)d_in[5];
    const float* ln_b   = (const float*)d_in[6];
    const float* w_off  = (const float*)d_in[7];
    const float* b_off  = (const float*)d_in[8];
    const float* w_mask = (const float*)d_in[9];
    const float* b_mask = (const float*)d_in[10];
    const float* w_out  = (const float*)d_in[11];
    const float* b_out  = (const float*)d_in[12];
    const float* bn_g   = (const float*)d_in[13];
    const float* bn_b   = (const float*)d_in[14];
    const float* bn_mean= (const float*)d_in[15];
    const float* bn_var = (const float*)d_in[16];
    float* out = (float*)d_out;

    const size_t SZ = (size_t)MTOT * CH;                 // elements
    const size_t need_new =
        4 * SZ * sizeof(float)
        + 6 * (size_t)CH * CH * sizeof(unsigned short)
        + CH * sizeof(float);

    if (ws_size >= need_new) {
        // -------- main path: 5 dispatches (r13-verified best, 224.1 us) -----
        float* ws = (float*)d_ws;
        float* v    = ws;                                          // SZ f32
        unsigned short* xt_hi = (unsigned short*)(v + SZ);         // SZ us
        unsigned short* xt_lo = xt_hi + SZ;                        // SZ us
        unsigned short* fh    = xt_lo + SZ;                        // SZ us
        unsigned short* fl    = fh + SZ;                           // SZ us
        float* omb  = (float*)(fl + SZ);                           // SZ f32
        unsigned short* wt_hi  = (unsigned short*)(omb + SZ);
        unsigned short* wt_lo  = wt_hi + CH * CH;
        unsigned short* wt2_hi = wt_lo + CH * CH;
        unsigned short* wt2_lo = wt2_hi + CH * CH;
        unsigned short* wt3_hi = wt2_lo + CH * CH;
        unsigned short* wt3_lo = wt3_hi + CH * CH;
        float* bcat = (float*)(wt3_lo + CH * CH);                  // 256 f32
        unsigned short* sh = xt_hi;
        unsigned short* sl = xt_lo;

        prep_kernel<<<dim3(XTBLK + 48), dim3(256), 0, stream>>>(
            x, xt_hi, xt_lo, w_out, wt_hi, wt_lo, w_in, wt3_hi, wt3_lo,
            w_off, w_mask, b_off, b_mask, wt2_hi, wt2_lo, bcat);
        dw2_ln_gelu_split<<<dim3(DW2BLK), dim3(256), 0, stream>>>(
            xt_hi, xt_lo, dw_w, dw_b, ln_g, ln_b, fh, fl);
        gemm_dual64<<<dim3(2 * NBLKG), dim3(256), 0, stream>>>(
            xt_hi, xt_lo, wt3_hi, wt3_lo, b_in, v,
            fh, fl, wt2_hi, wt2_lo, bcat, omb);
        sample_kernel_omb_split<<<dim3(DWBLK), dim3(256), 0, stream>>>(v, omb, sh, sl);
        gemm_out_64x128<<<dim3(NBLKG), dim3(256), 0, stream>>>(
            sh, sl, wt_hi, wt_lo, b_out, bn_g, bn_b, bn_mean, bn_var, out);
    } else {
        // -------- fallback: round-5 verified path --------
        float* ws = (float*)d_ws;
        float* v    = ws;
        unsigned short* xt_hi = (unsigned short*)(v + SZ);
        unsigned short* xt_lo = xt_hi + SZ;
        unsigned short* fh    = xt_lo + SZ;
        unsigned short* fl    = fh + SZ;
        float* omb  = (float*)(fl + SZ);
        unsigned short* wt_hi  = (unsigned short*)(omb + SZ);
        unsigned short* wt_lo  = wt_hi + CH * CH;
        unsigned short* wt2_hi = wt_lo + CH * CH;
        unsigned short* wt2_lo = wt2_hi + CH * CH;
        unsigned short* wt3_hi = wt2_lo + CH * CH;
        unsigned short* wt3_lo = wt3_hi + CH * CH;
        float* bcat = (float*)(wt3_lo + CH * CH);
        unsigned short* sh = xt_hi;
        unsigned short* sl = xt_lo;

        wt_split_kernel<<<dim3(4, 4), dim3(256), 0, stream>>>(w_out, wt_hi, wt_lo);
        wt_split_kernel<<<dim3(4, 4), dim3(256), 0, stream>>>(w_in, wt3_hi, wt3_lo);
        wt2_split_kernel<<<dim3(16), dim3(256), 0, stream>>>(
            w_off, w_mask, b_off, b_mask, wt2_hi, wt2_lo, bcat);
        xt_split_kernel<<<dim3(HW/64, CH/64, BATCH), dim3(256), 0, stream>>>(x, xt_hi, xt_lo);
        gemm_in_mfma<<<dim3(MTOT/256, CH/64), dim3(256), 0, stream>>>(
            xt_hi, xt_lo, wt3_hi, wt3_lo, b_in, v);
        dw_ln_gelu_nhwc_split<<<dim3(DWBLK), dim3(256), 0, stream>>>(
            xt_hi, xt_lo, dw_w, dw_b, ln_g, ln_b, fh, fl);
        gemm_in_mfma<<<dim3(MTOT/256, CH/64), dim3(256), 0, stream>>>(
            fh, fl, wt2_hi, wt2_lo, bcat, omb);
        sample_kernel_omb_split<<<dim3(DWBLK), dim3(256), 0, stream>>>(v, omb, sh, sl);
        gemm_out_bf16<<<dim3(MTOT/256, CH/64), dim3(256), 0, stream>>>(
            sh, sl, wt_hi, wt_lo, b_out, bn_g, bn_b, bn_mean, bn_var, out);
    }
}